// Round 8
// baseline (18276.991 us; speedup 1.0000x reference)
//
#include <hip/hip_runtime.h>
#include <math.h>

#define TM1 2047
#define NB 32
#define NV 21
#define HH 336
#define G3 1008
#define FLG_STRIDE 32   // ints per flag slot (128B)
#define GU 8
#define UU 42
#define SCAN_T 512
#define RING 256        // y0 ring depth (power of 2)

__device__ __forceinline__ float elu_f(float x){ return x > 0.f ? x : (expf(x) - 1.f); }
__device__ __forceinline__ float sigm_f(float x){ return 1.f / (1.f + expf(-x)); }

// ---------------- quaternion -> euler (zyx) + time-normalize ----------------
__global__ __launch_bounds__(256) void k_euler(const float* __restrict__ xd, float* __restrict__ xout){
  int b = blockIdx.x / NV, v = blockIdx.x % NV;
  const float* q = xd + ((size_t)b * 84 + 4 * v) * TM1;
  float ex[8], ey[8], ez[8];
  float sx = 0.f, sy = 0.f, sz = 0.f;
#pragma unroll
  for(int it = 0; it < 8; ++it){
    int t = threadIdx.x + it * 256;
    float e0 = 0.f, e1 = 0.f, e2 = 0.f;
    if(t < TM1){
      float q0 = q[t], q1 = q[TM1 + t], q2 = q[2 * TM1 + t], q3 = q[3 * TM1 + t];
      e0 = atan2f(2.f * (q0 * q1 - q2 * q3), 1.f - 2.f * (q1 * q1 + q2 * q2));
      float s = 2.f * (q1 * q3 + q0 * q2);
      s = fminf(1.f, fmaxf(-1.f, s));
      e1 = asinf(s);
      e2 = atan2f(2.f * (q0 * q3 - q1 * q2), 1.f - 2.f * (q2 * q2 + q3 * q3));
    }
    ex[it] = e0; ey[it] = e1; ez[it] = e2;
    sx += e0 * e0; sy += e1 * e1; sz += e2 * e2;
  }
  __shared__ float rb[3][256];
  rb[0][threadIdx.x] = sx; rb[1][threadIdx.x] = sy; rb[2][threadIdx.x] = sz;
  __syncthreads();
  if(threadIdx.x < 3){
    float s = 0.f;
    for(int i = 0; i < 256; ++i) s += rb[threadIdx.x][i];
    rb[threadIdx.x][0] = 1.f / fmaxf(sqrtf(s), 1e-12f);
  }
  __syncthreads();
  float i0 = rb[0][0], i1 = rb[1][0], i2 = rb[2][0];
  float* xo = xout + ((size_t)b * 63 + 3 * v) * TM1;
#pragma unroll
  for(int it = 0; it < 8; ++it){
    int t = threadIdx.x + it * 256;
    if(t < TM1){
      xo[t]            = ex[it] * i0;
      xo[TM1 + t]      = ey[it] * i1;
      xo[2 * TM1 + t]  = ez[it] * i2;
    }
  }
}

// ---------------- fused 2-layer persistent GRU scan ----------------
// 256 WGs: blocks 0..127 = layer 0, 128..255 = layer 1 (concurrent, L1 trails).
// Per layer: 8 unit-slices (42 units) x 16 batch-pairs. Whh (+Wih) in VGPRs.
// Input projections computed on the fly (L0 from x_ws, L1 from y0 ring).
// Sync: per-WG flags (128B apart), relaxed agent-scope atomics (LLC-coherent).
// y0 ring with backpressure: L0 step t waits flag1 >= t-RING+1 before reusing slot.
__global__ __launch_bounds__(SCAN_T) void k_fused(
    const float* __restrict__ Whh0, const float* __restrict__ bhh0,
    const float* __restrict__ Wih0, const float* __restrict__ bih0,
    const float* __restrict__ Whh1, const float* __restrict__ bhh1,
    const float* __restrict__ Wih1, const float* __restrict__ bih1,
    const float* __restrict__ x_ws,
    float* h0b, float* h1b, float* y0r, float* __restrict__ y1,
    float* hT0, float* hT1, int* flg0, int* flg1){
  int lay = blockIdx.x >> 7;
  int idx = blockIdx.x & 127;
  int ug = idx >> 4, pr = idx & 15;
  int u0 = ug * UU, b0 = pr * 2;
  int tid = threadIdx.x;
  int* f0 = flg0 + pr * (GU * FLG_STRIDE);
  int* f1 = flg1 + pr * (GU * FLG_STRIDE);
  __shared__ float hl[2][HH];
  __shared__ float yl[2][HH];           // L1: y0[t]; L0: x[t] (63 ch, slot 63 zeroed)
  __shared__ float part_h[3*UU][4][2];
  __shared__ float part_x[3*UU][4][2];

  int r = tid >> 2, kq = tid & 3;
  bool act = (tid < 3 * UU * 4);        // 504
  bool comb = (tid < 2 * UU);           // 84
  int cu = tid % UU, cb = tid / UU;

  if(lay == 0){
    // ---------- layer 0 ----------
    float wh[84], wx[16];
    if(act){
      int rglob = (r / UU) * HH + u0 + (r % UU);
      const float* wp = Whh0 + (size_t)rglob * HH + kq * 84;
#pragma unroll
      for(int j = 0; j < 84; ++j) wh[j] = wp[j];
      int k0 = kq * 16;
      int xlen = 63 - k0; if(xlen > 16) xlen = 16;
      const float* wq = Wih0 + (size_t)rglob * 63 + k0;
#pragma unroll
      for(int j = 0; j < 16; ++j) wx[j] = (j < xlen) ? wq[j] : 0.f;
    }
    float bh_r=0.f,bh_z=0.f,bh_n=0.f,bx_r=0.f,bx_z=0.f,bx_n=0.f;
    if(comb){
      bh_r = bhh0[u0+cu]; bh_z = bhh0[HH+u0+cu]; bh_n = bhh0[2*HH+u0+cu];
      bx_r = bih0[u0+cu]; bx_z = bih0[HH+u0+cu]; bx_n = bih0[2*HH+u0+cu];
    }
    if(tid == 508){ yl[0][63] = 0.f; yl[1][63] = 0.f; }   // pad slot for kq=3 tail
    for(int t = 0; t < TM1; ++t){
      if(t > 0 && tid < GU){            // peer h0 ready?
        while(__hip_atomic_load(f0 + tid*FLG_STRIDE, __ATOMIC_RELAXED, __HIP_MEMORY_SCOPE_AGENT) < t)
          __builtin_amdgcn_s_sleep(1);
      }
      if(t >= RING && tid >= 64 && tid < 64 + GU){   // ring slot consumed by L1?
        while(__hip_atomic_load(f1 + (tid-64)*FLG_STRIDE, __ATOMIC_RELAXED, __HIP_MEMORY_SCOPE_AGENT) < t - RING + 1)
          __builtin_amdgcn_s_sleep(1);
      }
      __syncthreads();
      float* hcur = h0b + (size_t)(t & 1) * NB * HH;
      float* hnxt = h0b + (size_t)((t + 1) & 1) * NB * HH;
      for(int i2 = tid; i2 < 2*HH; i2 += SCAN_T){
        int bs = (i2 >= HH), k = i2 - bs*HH;
        hl[bs][k] = __hip_atomic_load(&hcur[(size_t)(b0+bs)*HH + k],
                                      __ATOMIC_RELAXED, __HIP_MEMORY_SCOPE_AGENT);
      }
      if(tid >= 384 && tid < 510){      // x[t]: immutable, regular (L2-cached) loads
        int q = tid - 384; int cbx = q / 63, ch = q - cbx * 63;
        yl[cbx][ch] = x_ws[((size_t)(b0+cbx)*63 + ch)*TM1 + t];
      }
      __syncthreads();
      if(act){
        float a0 = 0.f, a1 = 0.f;
#pragma unroll
        for(int jj = 0; jj < 21; ++jj){
          float4 h0 = *(const float4*)&hl[0][kq*84 + jj*4];
          float4 h1 = *(const float4*)&hl[1][kq*84 + jj*4];
          a0 += wh[jj*4+0]*h0.x + wh[jj*4+1]*h0.y + wh[jj*4+2]*h0.z + wh[jj*4+3]*h0.w;
          a1 += wh[jj*4+0]*h1.x + wh[jj*4+1]*h1.y + wh[jj*4+2]*h1.z + wh[jj*4+3]*h1.w;
        }
        part_h[r][kq][0] = a0; part_h[r][kq][1] = a1;
        float c0 = 0.f, c1 = 0.f;
        int k0 = kq * 16;
#pragma unroll
        for(int j = 0; j < 16; ++j){
          c0 += wx[j] * yl[0][k0 + j];
          c1 += wx[j] * yl[1][k0 + j];
        }
        part_x[r][kq][0] = c0; part_x[r][kq][1] = c1;
      }
      __syncthreads();
      float hnew = 0.f;
      if(comb){
        float ghr = part_h[cu][0][cb]+part_h[cu][1][cb]+part_h[cu][2][cb]+part_h[cu][3][cb] + bh_r;
        float gxr = part_x[cu][0][cb]+part_x[cu][1][cb]+part_x[cu][2][cb]+part_x[cu][3][cb] + bx_r;
        float ghz = part_h[UU+cu][0][cb]+part_h[UU+cu][1][cb]+part_h[UU+cu][2][cb]+part_h[UU+cu][3][cb] + bh_z;
        float gxz = part_x[UU+cu][0][cb]+part_x[UU+cu][1][cb]+part_x[UU+cu][2][cb]+part_x[UU+cu][3][cb] + bx_z;
        float ghn = part_h[2*UU+cu][0][cb]+part_h[2*UU+cu][1][cb]+part_h[2*UU+cu][2][cb]+part_h[2*UU+cu][3][cb] + bh_n;
        float gxn = part_x[2*UU+cu][0][cb]+part_x[2*UU+cu][1][cb]+part_x[2*UU+cu][2][cb]+part_x[2*UU+cu][3][cb] + bx_n;
        float rg = sigm_f(gxr + ghr);
        float zg = sigm_f(gxz + ghz);
        float ng = tanhf(gxn + rg * ghn);
        hnew = (1.f - zg) * ng + zg * hl[cb][u0 + cu];
        __hip_atomic_store(&hnxt[(size_t)(b0+cb)*HH + u0+cu], hnew,
                           __ATOMIC_RELAXED, __HIP_MEMORY_SCOPE_AGENT);
        __hip_atomic_store(&y0r[((size_t)(b0+cb)*RING + (t & (RING-1)))*HH + u0+cu], hnew,
                           __ATOMIC_RELAXED, __HIP_MEMORY_SCOPE_AGENT);
      }
      __syncthreads();                  // vmcnt(0): h + ring stores acked at LLC
      if(tid == 0)
        __hip_atomic_store(f0 + ug*FLG_STRIDE, t + 1,
                           __ATOMIC_RELAXED, __HIP_MEMORY_SCOPE_AGENT);
      if(comb && t == TM1-1) hT0[(size_t)(b0+cb)*HH + u0+cu] = hnew;
    }
  } else {
    // ---------- layer 1 (trails layer 0) ----------
    float wh[84], wx[84];
    if(act){
      int rglob = (r / UU) * HH + u0 + (r % UU);
      const float* wp = Whh1 + (size_t)rglob * HH + kq * 84;
      const float* wq = Wih1 + (size_t)rglob * HH + kq * 84;
#pragma unroll
      for(int j = 0; j < 84; ++j){ wh[j] = wp[j]; wx[j] = wq[j]; }
    }
    float bh_r=0.f,bh_z=0.f,bh_n=0.f,bx_r=0.f,bx_z=0.f,bx_n=0.f;
    if(comb){
      bh_r = bhh1[u0+cu]; bh_z = bhh1[HH+u0+cu]; bh_n = bhh1[2*HH+u0+cu];
      bx_r = bih1[u0+cu]; bx_z = bih1[HH+u0+cu]; bx_n = bih1[2*HH+u0+cu];
    }
    for(int t = 0; t < TM1; ++t){
      if(tid < GU){                     // y0[t] ready? (L0 finished step t)
        while(__hip_atomic_load(f0 + tid*FLG_STRIDE, __ATOMIC_RELAXED, __HIP_MEMORY_SCOPE_AGENT) < t + 1)
          __builtin_amdgcn_s_sleep(1);
      }
      if(t > 0 && tid >= 64 && tid < 64 + GU){       // peer h1 ready?
        while(__hip_atomic_load(f1 + (tid-64)*FLG_STRIDE, __ATOMIC_RELAXED, __HIP_MEMORY_SCOPE_AGENT) < t)
          __builtin_amdgcn_s_sleep(1);
      }
      __syncthreads();
      float* hcur = h1b + (size_t)(t & 1) * NB * HH;
      float* hnxt = h1b + (size_t)((t + 1) & 1) * NB * HH;
      for(int i2 = tid; i2 < 2*HH; i2 += SCAN_T){
        int bs = (i2 >= HH), k = i2 - bs*HH;
        hl[bs][k] = __hip_atomic_load(&hcur[(size_t)(b0+bs)*HH + k],
                                      __ATOMIC_RELAXED, __HIP_MEMORY_SCOPE_AGENT);
        yl[bs][k] = __hip_atomic_load(&y0r[((size_t)(b0+bs)*RING + (t & (RING-1)))*HH + k],
                                      __ATOMIC_RELAXED, __HIP_MEMORY_SCOPE_AGENT);
      }
      __syncthreads();
      if(act){
        float a0=0.f, a1=0.f, c0=0.f, c1=0.f;
#pragma unroll
        for(int jj = 0; jj < 21; ++jj){
          float4 h0 = *(const float4*)&hl[0][kq*84 + jj*4];
          float4 h1 = *(const float4*)&hl[1][kq*84 + jj*4];
          float4 y0v = *(const float4*)&yl[0][kq*84 + jj*4];
          float4 y1v = *(const float4*)&yl[1][kq*84 + jj*4];
          float w0 = wh[jj*4+0], w1 = wh[jj*4+1], w2 = wh[jj*4+2], w3 = wh[jj*4+3];
          a0 += w0*h0.x + w1*h0.y + w2*h0.z + w3*h0.w;
          a1 += w0*h1.x + w1*h1.y + w2*h1.z + w3*h1.w;
          float v0 = wx[jj*4+0], v1 = wx[jj*4+1], v2 = wx[jj*4+2], v3 = wx[jj*4+3];
          c0 += v0*y0v.x + v1*y0v.y + v2*y0v.z + v3*y0v.w;
          c1 += v0*y1v.x + v1*y1v.y + v2*y1v.z + v3*y1v.w;
        }
        part_h[r][kq][0] = a0; part_h[r][kq][1] = a1;
        part_x[r][kq][0] = c0; part_x[r][kq][1] = c1;
      }
      __syncthreads();
      float hnew = 0.f;
      if(comb){
        float ghr = part_h[cu][0][cb]+part_h[cu][1][cb]+part_h[cu][2][cb]+part_h[cu][3][cb] + bh_r;
        float gxr = part_x[cu][0][cb]+part_x[cu][1][cb]+part_x[cu][2][cb]+part_x[cu][3][cb] + bx_r;
        float ghz = part_h[UU+cu][0][cb]+part_h[UU+cu][1][cb]+part_h[UU+cu][2][cb]+part_h[UU+cu][3][cb] + bh_z;
        float gxz = part_x[UU+cu][0][cb]+part_x[UU+cu][1][cb]+part_x[UU+cu][2][cb]+part_x[UU+cu][3][cb] + bx_z;
        float ghn = part_h[2*UU+cu][0][cb]+part_h[2*UU+cu][1][cb]+part_h[2*UU+cu][2][cb]+part_h[2*UU+cu][3][cb] + bh_n;
        float gxn = part_x[2*UU+cu][0][cb]+part_x[2*UU+cu][1][cb]+part_x[2*UU+cu][2][cb]+part_x[2*UU+cu][3][cb] + bx_n;
        float rg = sigm_f(gxr + ghr);
        float zg = sigm_f(gxz + ghz);
        float ng = tanhf(gxn + rg * ghn);
        hnew = (1.f - zg) * ng + zg * hl[cb][u0 + cu];
        __hip_atomic_store(&hnxt[(size_t)(b0+cb)*HH + u0+cu], hnew,
                           __ATOMIC_RELAXED, __HIP_MEMORY_SCOPE_AGENT);
      }
      __syncthreads();                  // vmcnt(0): h store acked at LLC
      if(tid == 0)
        __hip_atomic_store(f1 + ug*FLG_STRIDE, t + 1,
                           __ATOMIC_RELAXED, __HIP_MEMORY_SCOPE_AGENT);
      if(comb){                         // off critical path (drains during next spin)
        y1[((size_t)(b0+cb)*TM1 + t)*HH + u0+cu] = hnew;
        if(t == TM1-1) hT1[(size_t)(b0+cb)*HH + u0+cu] = hnew;
      }
    }
  }
}

// ---------------- fused conv stack + dense head (32-t tile, static LDS 45.6KB) ----------------
__global__ __launch_bounds__(256) void k_head(const float* __restrict__ y1,
   const float* __restrict__ W2, const float* __restrict__ b2,
   const float* __restrict__ W3, const float* __restrict__ b3,
   const float* __restrict__ W3z, const float* __restrict__ b3z,
   const float* __restrict__ Wza, const float* __restrict__ bza,
   const float* __restrict__ W4, const float* __restrict__ b4,
   const float* __restrict__ W5, const float* __restrict__ b5,
   const float* __restrict__ gmm, const float* __restrict__ bet,
   const float* __restrict__ Wc, const float* __restrict__ bc,
   float* __restrict__ out_affs, float* __restrict__ out_lab){
  __shared__ float sm[11402];
  float* aggp = sm;             // [5*32][38]  6080
  float* zinp = sm + 6080;      // [64][36]    2304
  float* zzp  = sm + 8384;      // [64][34]    2176 -> ends 10560
  float* ystp = sm + 10560;     // [42][17]    714  -> ends 11274
  float* affp = sm + 11274;     // [4][32]     128  -> ends 11402
  float* lblA = sm + 6080;      // [128][32]   4096 (aliases zin+zz, dead by then)
  float* lgpp = sm;             // [32][8][4]  1024 (aliases aggp, dead by then)
  int t0 = blockIdx.x * 32;
  int b  = blockIdx.y;
  int tid = threadIdx.x;

  for(int i = tid; i < 6080; i += 256) aggp[i] = 0.f;
  for(int i = tid; i < 2304; i += 256) zinp[i] = 0.f;
  __syncthreads();

  const int   vg_[21] = {0,3,3,3,3,4,4,4,4,0,0,0,0,1,1,1,1,2,2,2,2};
  const float vw_[21] = {0.1f,0.1f,0.2f,0.3f,0.4f,0.1f,0.2f,0.3f,0.4f,
                         0.1f,0.2f,0.2f,0.4f,0.1f,0.2f,0.3f,0.4f,0.1f,0.2f,0.3f,0.4f};

  // --- per-joint conv(k5,p2)+elu, group-weighted accumulate into aggp ---
  {
    int o = tid >> 3, q = tid & 7;                 // o<32, ts = q*5+j
    for(int v = 0; v < NV; ++v){
      for(int idx = tid; idx < 42 * 16; idx += 256){
        int ts = idx >> 4, i = idx & 15; int t = t0 - 5 + ts;
        ystp[ts * 17 + i] = (t >= 0 && t < TM1) ? y1[((size_t)b * TM1 + t) * HH + v * 16 + i] : 0.f;
      }
      __syncthreads();
      int g = vg_[v]; float wv = vw_[v];
      const float* wp = W2 + v * 2560 + o * 80;
      float acc5[5];
      float bias = b2[v * 32 + o];
#pragma unroll
      for(int j = 0; j < 5; ++j) acc5[j] = bias;
#pragma unroll
      for(int i = 0; i < 16; ++i){
        float w0 = wp[i*5+0], w1 = wp[i*5+1], w2v = wp[i*5+2], w3v = wp[i*5+3], w4v = wp[i*5+4];
#pragma unroll
        for(int j = 0; j < 5; ++j){
          int ts = q * 5 + j;
          if(ts < 38){
            acc5[j] += w0*ystp[ts*17+i] + w1*ystp[(ts+1)*17+i] + w2v*ystp[(ts+2)*17+i]
                     + w3v*ystp[(ts+3)*17+i] + w4v*ystp[(ts+4)*17+i];
          }
        }
      }
#pragma unroll
      for(int j = 0; j < 5; ++j){
        int ts = q * 5 + j;
        if(ts < 38){
          int t = t0 - 3 + ts;
          if(t >= 0 && t < TM1) aggp[(g * 32 + o) * 38 + ts] += wv * elu_f(acc5[j]);
        }
      }
      __syncthreads();
    }
  }

  // --- 5x group conv(k3,p1)+elu, weighted sum into zinp ---
  {
    int c = tid >> 2, q = tid & 3;                 // c<64, ts = q*9+j (36)
    for(int k5 = 0; k5 < 5; ++k5){
      float coef = (k5 == 0) ? 0.12f : 0.22f;
      const float* wp = W3 + k5 * 6144 + c * 96;
      float accv[9];
      float bias = b3[k5 * 64 + c];
#pragma unroll
      for(int j = 0; j < 9; ++j) accv[j] = bias;
      for(int i = 0; i < 32; ++i){
        float w0 = wp[i*3+0], w1 = wp[i*3+1], w2v = wp[i*3+2];
        const float* ap = &aggp[(k5 * 32 + i) * 38 + q * 9];
#pragma unroll
        for(int j = 0; j < 9; ++j)
          accv[j] += w0*ap[j] + w1*ap[j+1] + w2v*ap[j+2];
      }
      __syncthreads();
#pragma unroll
      for(int j = 0; j < 9; ++j){
        int ts = q * 9 + j;
        int t = t0 - 2 + ts;
        if(t >= 0 && t < TM1) zinp[c * 36 + ts] += coef * elu_f(accv[j]);
      }
      __syncthreads();
    }
  }

  // --- conv(k3,p1)+elu -> z (zzp) ---
  {
    int c = tid >> 2, q = tid & 3;                 // ts = q*9+j, guard <34
    const float* wp = W3z + c * 192;
    float accv[9];
    float bias = b3z[c];
#pragma unroll
    for(int j = 0; j < 9; ++j) accv[j] = bias;
    for(int i = 0; i < 64; ++i){
      float w0 = wp[i*3+0], w1 = wp[i*3+1], w2v = wp[i*3+2];
      const float* zp = &zinp[i * 36 + q * 9];
#pragma unroll
      for(int j = 0; j < 9; ++j)
        accv[j] += w0*zp[j] + w1*zp[j+1] + w2v*zp[j+2];
    }
    __syncthreads();
#pragma unroll
    for(int j = 0; j < 9; ++j){
      int ts = q * 9 + j;
      if(ts < 34){
        int t = t0 - 1 + ts;
        zzp[c * 34 + ts] = (t >= 0 && t < TM1) ? elu_f(accv[j]) : 0.f;
      }
    }
    __syncthreads();
  }

  // --- affs conv(k3,p1)+elu (output, transposed) ---
  if(tid < 128){
    int a = tid >> 5, tt = tid & 31;
    const float* wp = Wza + a * 192;
    float acc = bza[a];
    for(int i = 0; i < 64; ++i){
      const float* zp = &zzp[i * 34 + tt];
      acc += wp[i*3+0]*zp[0] + wp[i*3+1]*zp[1] + wp[i*3+2]*zp[2];
    }
    float av = elu_f(acc);
    affp[a * 32 + tt] = av;
    int t = t0 + tt;
    if(t < TM1) out_affs[((size_t)b * TM1 + t) * 4 + a] = av;
  }
  __syncthreads();

  // --- lbl1 = elu(W4 . affs + b4) -> lblA[128][32] (overwrites zin/zz) ---
  for(int idx = tid; idx < 4096; idx += 256){
    int d = idx >> 5, tt = idx & 31;
    float acc = b4[d] + W4[d*4+0]*affp[tt] + W4[d*4+1]*affp[32+tt]
              + W4[d*4+2]*affp[64+tt] + W4[d*4+3]*affp[96+tt];
    lblA[idx] = elu_f(acc);
  }
  __syncthreads();

  // --- lbl2 = elu(W5 . lbl1 + b5); BN over t; logits; sigmoid ---
  {
    int tt = tid >> 3, dg = tid & 7;               // d = dg*16+dd
    float l2[16];
#pragma unroll
    for(int dd = 0; dd < 16; ++dd) l2[dd] = b5[dg * 16 + dd];
    for(int cc = 0; cc < 128; ++cc){
      float xv = lblA[cc * 32 + tt];
#pragma unroll
      for(int dd = 0; dd < 16; ++dd)
        l2[dd] += W5[(dg * 16 + dd) * 128 + cc] * xv;
    }
    int t = t0 + tt;
    float sc = 0.f, bb = 0.f;
    if(t < TM1){ sc = gmm[t] * rsqrtf(1.f + 1e-5f); bb = bet[t]; }
    float lg[4] = {0.f, 0.f, 0.f, 0.f};
#pragma unroll
    for(int dd = 0; dd < 16; ++dd){
      int d = dg * 16 + dd;
      float val = elu_f(l2[dd]) * sc + bb;
#pragma unroll
      for(int c = 0; c < 4; ++c) lg[c] += Wc[c * 128 + d] * val;
    }
    __syncthreads();
#pragma unroll
    for(int c = 0; c < 4; ++c) lgpp[(tt * 8 + dg) * 4 + c] = lg[c];
  }
  __syncthreads();
  if(tid < 128){
    int tt = tid >> 2, c = tid & 3;
    float s = bc[c];
#pragma unroll
    for(int dg = 0; dg < 8; ++dg) s += lgpp[(tt * 8 + dg) * 4 + c];
    int ta = t0 + tt;
    if(ta < TM1) out_lab[((size_t)b * TM1 + ta) * 4 + c] = sigm_f(s);
  }
}

extern "C" void kernel_launch(void* const* d_in, const int* in_sizes, int n_in,
                              void* d_out, int out_size, void* d_ws, size_t ws_size,
                              hipStream_t stream){
  (void)in_sizes; (void)n_in; (void)out_size; (void)ws_size;
  const float* x_diffs = (const float*)d_in[1];
  const float* h_init  = (const float*)d_in[3];
  const float* Wih0 = (const float*)d_in[4];
  const float* Whh0 = (const float*)d_in[5];
  const float* bih0 = (const float*)d_in[6];
  const float* bhh0 = (const float*)d_in[7];
  const float* Wih1 = (const float*)d_in[8];
  const float* Whh1 = (const float*)d_in[9];
  const float* bih1 = (const float*)d_in[10];
  const float* bhh1 = (const float*)d_in[11];
  const float* W2  = (const float*)d_in[12];
  const float* b2  = (const float*)d_in[13];
  const float* W3  = (const float*)d_in[14];
  const float* b3  = (const float*)d_in[15];
  const float* W3z = (const float*)d_in[16];
  const float* b3z = (const float*)d_in[17];
  const float* Wza = (const float*)d_in[18];
  const float* bza = (const float*)d_in[19];
  const float* W4  = (const float*)d_in[20];
  const float* b4  = (const float*)d_in[21];
  const float* W5  = (const float*)d_in[22];
  const float* b5  = (const float*)d_in[23];
  const float* gmm = (const float*)d_in[24];
  const float* bet = (const float*)d_in[25];
  const float* Wc  = (const float*)d_in[26];
  const float* bc  = (const float*)d_in[27];
  float* out = (float*)d_out;

  // workspace layout (floats): ~116 MB total
  float* ws   = (float*)d_ws;
  float* x_ws = ws;                       // 32*63*2047      = 4,126,752
  float* y1   = x_ws + 4126752;           // 32*2047*336     = 22,009,344
  float* y0r  = y1 + 22009344;            // 32*RING*336     =  2,752,512
  float* hb   = y0r + 2752512;            // 4*32*336        =     43,008
  int*   flg  = (int*)(hb + 43008);       // 2 * 16 * GU * FLG_STRIDE ints

  float* h0b = hb;                        // two buffers: hb, hb + NB*HH
  float* h1b = hb + 2 * NB * HH;

  float* out_affs = out;
  float* out_lab  = out + (size_t)NB * TM1 * 4;
  float* hT0 = out + 2 * (size_t)NB * TM1 * 4;
  float* hT1 = hT0 + NB * HH;

  (void)hipMemsetAsync(flg, 0, 2 * 16 * GU * FLG_STRIDE * sizeof(int), stream);
  (void)hipMemcpyAsync(h0b, h_init,           NB * HH * sizeof(float), hipMemcpyDeviceToDevice, stream);
  (void)hipMemcpyAsync(h1b, h_init + NB * HH, NB * HH * sizeof(float), hipMemcpyDeviceToDevice, stream);

  k_euler<<<dim3(NB * NV), 256, 0, stream>>>(x_diffs, x_ws);

  k_fused<<<dim3(256), SCAN_T, 0, stream>>>(
      Whh0, bhh0, Wih0, bih0, Whh1, bhh1, Wih1, bih1, x_ws,
      h0b, h1b, y0r, y1, hT0, hT1,
      flg, flg + 16 * GU * FLG_STRIDE);

  k_head<<<dim3(64, NB), 256, 0, stream>>>(y1, W2, b2, W3, b3, W3z, b3z, Wza, bza,
                                           W4, b4, W5, b5, gmm, bet, Wc, bc,
                                           out_affs, out_lab);
}

// Round 9
// 17936.620 us; speedup vs baseline: 1.0190x; 1.0190x over previous
//
#include <hip/hip_runtime.h>
#include <math.h>

#define TM1 2047
#define NB 32
#define NV 21
#define HH 336
#define G3 1008
#define FLG_STRIDE 32   // ints per flag slot (128B)
#define GU 8
#define UU 42
#define SCAN_T 512
#define RING 256        // y0 ring depth (power of 2)

__device__ __forceinline__ float elu_f(float x){ return x > 0.f ? x : (expf(x) - 1.f); }
__device__ __forceinline__ float sigm_f(float x){ return 1.f / (1.f + expf(-x)); }

// ---------------- quaternion -> euler (zyx) + time-normalize ----------------
__global__ __launch_bounds__(256) void k_euler(const float* __restrict__ xd, float* __restrict__ xout){
  int b = blockIdx.x / NV, v = blockIdx.x % NV;
  const float* q = xd + ((size_t)b * 84 + 4 * v) * TM1;
  float ex[8], ey[8], ez[8];
  float sx = 0.f, sy = 0.f, sz = 0.f;
#pragma unroll
  for(int it = 0; it < 8; ++it){
    int t = threadIdx.x + it * 256;
    float e0 = 0.f, e1 = 0.f, e2 = 0.f;
    if(t < TM1){
      float q0 = q[t], q1 = q[TM1 + t], q2 = q[2 * TM1 + t], q3 = q[3 * TM1 + t];
      e0 = atan2f(2.f * (q0 * q1 - q2 * q3), 1.f - 2.f * (q1 * q1 + q2 * q2));
      float s = 2.f * (q1 * q3 + q0 * q2);
      s = fminf(1.f, fmaxf(-1.f, s));
      e1 = asinf(s);
      e2 = atan2f(2.f * (q0 * q3 - q1 * q2), 1.f - 2.f * (q2 * q2 + q3 * q3));
    }
    ex[it] = e0; ey[it] = e1; ez[it] = e2;
    sx += e0 * e0; sy += e1 * e1; sz += e2 * e2;
  }
  __shared__ float rb[3][256];
  rb[0][threadIdx.x] = sx; rb[1][threadIdx.x] = sy; rb[2][threadIdx.x] = sz;
  __syncthreads();
  if(threadIdx.x < 3){
    float s = 0.f;
    for(int i = 0; i < 256; ++i) s += rb[threadIdx.x][i];
    rb[threadIdx.x][0] = 1.f / fmaxf(sqrtf(s), 1e-12f);
  }
  __syncthreads();
  float i0 = rb[0][0], i1 = rb[1][0], i2 = rb[2][0];
  float* xo = xout + ((size_t)b * 63 + 3 * v) * TM1;
#pragma unroll
  for(int it = 0; it < 8; ++it){
    int t = threadIdx.x + it * 256;
    if(t < TM1){
      xo[t]            = ex[it] * i0;
      xo[TM1 + t]      = ey[it] * i1;
      xo[2 * TM1 + t]  = ez[it] * i2;
    }
  }
}

// ---------------- fused 2-layer persistent GRU scan ----------------
// 256 WGs: blocks 0..127 = layer 0, 128..255 = layer 1 (concurrent, L1 trails).
// Per layer: 8 unit-slices (42 units) x 16 batch-pairs. Whh (+Wih) in VGPRs.
// __launch_bounds__(512, 2): 2 waves/EU -> 256-VGPR budget. REQUIRED: L1 holds
// wh[84]+wx[84]=168 weight VGPRs/thread; the default 128-cap spilled them to
// scratch and tripled per-step latency (round-8 regression, VGPR_Count=128).
// Sync: per-WG flags (128B apart), relaxed agent-scope atomics (LLC-coherent).
// y0 ring with backpressure: L0 step t waits flag1 >= t-RING+1 before reusing slot.
__global__ __launch_bounds__(SCAN_T, 2) void k_fused(
    const float* __restrict__ Whh0, const float* __restrict__ bhh0,
    const float* __restrict__ Wih0, const float* __restrict__ bih0,
    const float* __restrict__ Whh1, const float* __restrict__ bhh1,
    const float* __restrict__ Wih1, const float* __restrict__ bih1,
    const float* __restrict__ x_ws,
    float* h0b, float* h1b, float* y0r, float* __restrict__ y1,
    float* hT0, float* hT1, int* flg0, int* flg1){
  int lay = blockIdx.x >> 7;
  int idx = blockIdx.x & 127;
  int ug = idx >> 4, pr = idx & 15;
  int u0 = ug * UU, b0 = pr * 2;
  int tid = threadIdx.x;
  int* f0 = flg0 + pr * (GU * FLG_STRIDE);
  int* f1 = flg1 + pr * (GU * FLG_STRIDE);
  __shared__ float hl[2][HH];
  __shared__ float yl[2][HH];           // L1: y0[t]; L0: x[t] (63 ch, slot 63 zeroed)
  __shared__ float part_h[3*UU][4][2];
  __shared__ float part_x[3*UU][4][2];

  int r = tid >> 2, kq = tid & 3;
  bool act = (tid < 3 * UU * 4);        // 504
  bool comb = (tid < 2 * UU);           // 84
  int cu = tid % UU, cb = tid / UU;

  if(lay == 0){
    // ---------- layer 0 ----------
    float wh[84], wx[16];
    if(act){
      int rglob = (r / UU) * HH + u0 + (r % UU);
      const float* wp = Whh0 + (size_t)rglob * HH + kq * 84;
#pragma unroll
      for(int j = 0; j < 84; ++j) wh[j] = wp[j];
      int k0 = kq * 16;
      int xlen = 63 - k0; if(xlen > 16) xlen = 16;
      const float* wq = Wih0 + (size_t)rglob * 63 + k0;
#pragma unroll
      for(int j = 0; j < 16; ++j) wx[j] = (j < xlen) ? wq[j] : 0.f;
    }
    float bh_r=0.f,bh_z=0.f,bh_n=0.f,bx_r=0.f,bx_z=0.f,bx_n=0.f;
    if(comb){
      bh_r = bhh0[u0+cu]; bh_z = bhh0[HH+u0+cu]; bh_n = bhh0[2*HH+u0+cu];
      bx_r = bih0[u0+cu]; bx_z = bih0[HH+u0+cu]; bx_n = bih0[2*HH+u0+cu];
    }
    bool xload = (tid >= 384 && tid < 510);
    int xq = tid - 384, xcb = xq / 63, xch = xq - xcb * 63;
    const float* xbase = x_ws + ((size_t)(b0 + xcb) * 63 + xch) * TM1;
    if(tid == 510){ yl[0][63] = 0.f; yl[1][63] = 0.f; }   // pad slot for kq=3 tail
    for(int t = 0; t < TM1; ++t){
      float xr = 0.f;
      if(xload) xr = xbase[t];          // immutable: prefetch before spin, hides latency
      if(t > 0 && tid < GU){            // peer h0 ready?
        while(__hip_atomic_load(f0 + tid*FLG_STRIDE, __ATOMIC_RELAXED, __HIP_MEMORY_SCOPE_AGENT) < t)
          __builtin_amdgcn_s_sleep(1);
      }
      if(t >= RING && tid >= 64 && tid < 64 + GU){   // ring slot consumed by L1?
        while(__hip_atomic_load(f1 + (tid-64)*FLG_STRIDE, __ATOMIC_RELAXED, __HIP_MEMORY_SCOPE_AGENT) < t - RING + 1)
          __builtin_amdgcn_s_sleep(1);
      }
      __syncthreads();
      float* hcur = h0b + (size_t)(t & 1) * NB * HH;
      float* hnxt = h0b + (size_t)((t + 1) & 1) * NB * HH;
      for(int i2 = tid; i2 < 2*HH; i2 += SCAN_T){
        int bs = (i2 >= HH), k = i2 - bs*HH;
        hl[bs][k] = __hip_atomic_load(&hcur[(size_t)(b0+bs)*HH + k],
                                      __ATOMIC_RELAXED, __HIP_MEMORY_SCOPE_AGENT);
      }
      if(xload) yl[xcb][xch] = xr;
      __syncthreads();
      if(act){
        float a0 = 0.f, a1 = 0.f;
#pragma unroll
        for(int jj = 0; jj < 21; ++jj){
          float4 h0 = *(const float4*)&hl[0][kq*84 + jj*4];
          float4 h1 = *(const float4*)&hl[1][kq*84 + jj*4];
          a0 += wh[jj*4+0]*h0.x + wh[jj*4+1]*h0.y + wh[jj*4+2]*h0.z + wh[jj*4+3]*h0.w;
          a1 += wh[jj*4+0]*h1.x + wh[jj*4+1]*h1.y + wh[jj*4+2]*h1.z + wh[jj*4+3]*h1.w;
        }
        part_h[r][kq][0] = a0; part_h[r][kq][1] = a1;
        float c0 = 0.f, c1 = 0.f;
        int k0 = kq * 16;
#pragma unroll
        for(int j = 0; j < 16; ++j){
          c0 += wx[j] * yl[0][k0 + j];
          c1 += wx[j] * yl[1][k0 + j];
        }
        part_x[r][kq][0] = c0; part_x[r][kq][1] = c1;
      }
      __syncthreads();
      float hnew = 0.f;
      if(comb){
        float ghr = part_h[cu][0][cb]+part_h[cu][1][cb]+part_h[cu][2][cb]+part_h[cu][3][cb] + bh_r;
        float gxr = part_x[cu][0][cb]+part_x[cu][1][cb]+part_x[cu][2][cb]+part_x[cu][3][cb] + bx_r;
        float ghz = part_h[UU+cu][0][cb]+part_h[UU+cu][1][cb]+part_h[UU+cu][2][cb]+part_h[UU+cu][3][cb] + bh_z;
        float gxz = part_x[UU+cu][0][cb]+part_x[UU+cu][1][cb]+part_x[UU+cu][2][cb]+part_x[UU+cu][3][cb] + bx_z;
        float ghn = part_h[2*UU+cu][0][cb]+part_h[2*UU+cu][1][cb]+part_h[2*UU+cu][2][cb]+part_h[2*UU+cu][3][cb] + bh_n;
        float gxn = part_x[2*UU+cu][0][cb]+part_x[2*UU+cu][1][cb]+part_x[2*UU+cu][2][cb]+part_x[2*UU+cu][3][cb] + bx_n;
        float rg = sigm_f(gxr + ghr);
        float zg = sigm_f(gxz + ghz);
        float ng = tanhf(gxn + rg * ghn);
        hnew = (1.f - zg) * ng + zg * hl[cb][u0 + cu];
        __hip_atomic_store(&hnxt[(size_t)(b0+cb)*HH + u0+cu], hnew,
                           __ATOMIC_RELAXED, __HIP_MEMORY_SCOPE_AGENT);
        __hip_atomic_store(&y0r[((size_t)(b0+cb)*RING + (t & (RING-1)))*HH + u0+cu], hnew,
                           __ATOMIC_RELAXED, __HIP_MEMORY_SCOPE_AGENT);
      }
      __syncthreads();                  // vmcnt(0): h + ring stores acked at LLC
      if(tid == 0)
        __hip_atomic_store(f0 + ug*FLG_STRIDE, t + 1,
                           __ATOMIC_RELAXED, __HIP_MEMORY_SCOPE_AGENT);
      if(comb && t == TM1-1) hT0[(size_t)(b0+cb)*HH + u0+cu] = hnew;
    }
  } else {
    // ---------- layer 1 (trails layer 0) ----------
    float wh[84], wx[84];
    if(act){
      int rglob = (r / UU) * HH + u0 + (r % UU);
      const float* wp = Whh1 + (size_t)rglob * HH + kq * 84;
      const float* wq = Wih1 + (size_t)rglob * HH + kq * 84;
#pragma unroll
      for(int j = 0; j < 84; ++j){ wh[j] = wp[j]; wx[j] = wq[j]; }
    }
    float bh_r=0.f,bh_z=0.f,bh_n=0.f,bx_r=0.f,bx_z=0.f,bx_n=0.f;
    if(comb){
      bh_r = bhh1[u0+cu]; bh_z = bhh1[HH+u0+cu]; bh_n = bhh1[2*HH+u0+cu];
      bx_r = bih1[u0+cu]; bx_z = bih1[HH+u0+cu]; bx_n = bih1[2*HH+u0+cu];
    }
    for(int t = 0; t < TM1; ++t){
      if(tid < GU){                     // y0[t] ready? (L0 finished step t)
        while(__hip_atomic_load(f0 + tid*FLG_STRIDE, __ATOMIC_RELAXED, __HIP_MEMORY_SCOPE_AGENT) < t + 1)
          __builtin_amdgcn_s_sleep(1);
      }
      if(t > 0 && tid >= 64 && tid < 64 + GU){       // peer h1 ready?
        while(__hip_atomic_load(f1 + (tid-64)*FLG_STRIDE, __ATOMIC_RELAXED, __HIP_MEMORY_SCOPE_AGENT) < t)
          __builtin_amdgcn_s_sleep(1);
      }
      __syncthreads();
      float* hcur = h1b + (size_t)(t & 1) * NB * HH;
      float* hnxt = h1b + (size_t)((t + 1) & 1) * NB * HH;
      for(int i2 = tid; i2 < 2*HH; i2 += SCAN_T){
        int bs = (i2 >= HH), k = i2 - bs*HH;
        hl[bs][k] = __hip_atomic_load(&hcur[(size_t)(b0+bs)*HH + k],
                                      __ATOMIC_RELAXED, __HIP_MEMORY_SCOPE_AGENT);
        yl[bs][k] = __hip_atomic_load(&y0r[((size_t)(b0+bs)*RING + (t & (RING-1)))*HH + k],
                                      __ATOMIC_RELAXED, __HIP_MEMORY_SCOPE_AGENT);
      }
      __syncthreads();
      if(act){
        float a0=0.f, a1=0.f, c0=0.f, c1=0.f;
#pragma unroll
        for(int jj = 0; jj < 21; ++jj){
          float4 h0 = *(const float4*)&hl[0][kq*84 + jj*4];
          float4 h1 = *(const float4*)&hl[1][kq*84 + jj*4];
          float4 y0v = *(const float4*)&yl[0][kq*84 + jj*4];
          float4 y1v = *(const float4*)&yl[1][kq*84 + jj*4];
          float w0 = wh[jj*4+0], w1 = wh[jj*4+1], w2 = wh[jj*4+2], w3 = wh[jj*4+3];
          a0 += w0*h0.x + w1*h0.y + w2*h0.z + w3*h0.w;
          a1 += w0*h1.x + w1*h1.y + w2*h1.z + w3*h1.w;
          float v0 = wx[jj*4+0], v1 = wx[jj*4+1], v2 = wx[jj*4+2], v3 = wx[jj*4+3];
          c0 += v0*y0v.x + v1*y0v.y + v2*y0v.z + v3*y0v.w;
          c1 += v0*y1v.x + v1*y1v.y + v2*y1v.z + v3*y1v.w;
        }
        part_h[r][kq][0] = a0; part_h[r][kq][1] = a1;
        part_x[r][kq][0] = c0; part_x[r][kq][1] = c1;
      }
      __syncthreads();
      float hnew = 0.f;
      if(comb){
        float ghr = part_h[cu][0][cb]+part_h[cu][1][cb]+part_h[cu][2][cb]+part_h[cu][3][cb] + bh_r;
        float gxr = part_x[cu][0][cb]+part_x[cu][1][cb]+part_x[cu][2][cb]+part_x[cu][3][cb] + bx_r;
        float ghz = part_h[UU+cu][0][cb]+part_h[UU+cu][1][cb]+part_h[UU+cu][2][cb]+part_h[UU+cu][3][cb] + bh_z;
        float gxz = part_x[UU+cu][0][cb]+part_x[UU+cu][1][cb]+part_x[UU+cu][2][cb]+part_x[UU+cu][3][cb] + bx_z;
        float ghn = part_h[2*UU+cu][0][cb]+part_h[2*UU+cu][1][cb]+part_h[2*UU+cu][2][cb]+part_h[2*UU+cu][3][cb] + bh_n;
        float gxn = part_x[2*UU+cu][0][cb]+part_x[2*UU+cu][1][cb]+part_x[2*UU+cu][2][cb]+part_x[2*UU+cu][3][cb] + bx_n;
        float rg = sigm_f(gxr + ghr);
        float zg = sigm_f(gxz + ghz);
        float ng = tanhf(gxn + rg * ghn);
        hnew = (1.f - zg) * ng + zg * hl[cb][u0 + cu];
        __hip_atomic_store(&hnxt[(size_t)(b0+cb)*HH + u0+cu], hnew,
                           __ATOMIC_RELAXED, __HIP_MEMORY_SCOPE_AGENT);
      }
      __syncthreads();                  // vmcnt(0): h store acked at LLC
      if(tid == 0)
        __hip_atomic_store(f1 + ug*FLG_STRIDE, t + 1,
                           __ATOMIC_RELAXED, __HIP_MEMORY_SCOPE_AGENT);
      if(comb){                         // off critical path (drains during next spin)
        y1[((size_t)(b0+cb)*TM1 + t)*HH + u0+cu] = hnew;
        if(t == TM1-1) hT1[(size_t)(b0+cb)*HH + u0+cu] = hnew;
      }
    }
  }
}

// ---------------- fused conv stack + dense head (32-t tile, static LDS 45.6KB) ----------------
__global__ __launch_bounds__(256) void k_head(const float* __restrict__ y1,
   const float* __restrict__ W2, const float* __restrict__ b2,
   const float* __restrict__ W3, const float* __restrict__ b3,
   const float* __restrict__ W3z, const float* __restrict__ b3z,
   const float* __restrict__ Wza, const float* __restrict__ bza,
   const float* __restrict__ W4, const float* __restrict__ b4,
   const float* __restrict__ W5, const float* __restrict__ b5,
   const float* __restrict__ gmm, const float* __restrict__ bet,
   const float* __restrict__ Wc, const float* __restrict__ bc,
   float* __restrict__ out_affs, float* __restrict__ out_lab){
  __shared__ float sm[11402];
  float* aggp = sm;             // [5*32][38]  6080
  float* zinp = sm + 6080;      // [64][36]    2304
  float* zzp  = sm + 8384;      // [64][34]    2176 -> ends 10560
  float* ystp = sm + 10560;     // [42][17]    714  -> ends 11274
  float* affp = sm + 11274;     // [4][32]     128  -> ends 11402
  float* lblA = sm + 6080;      // [128][32]   4096 (aliases zin+zz, dead by then)
  float* lgpp = sm;             // [32][8][4]  1024 (aliases aggp, dead by then)
  int t0 = blockIdx.x * 32;
  int b  = blockIdx.y;
  int tid = threadIdx.x;

  for(int i = tid; i < 6080; i += 256) aggp[i] = 0.f;
  for(int i = tid; i < 2304; i += 256) zinp[i] = 0.f;
  __syncthreads();

  const int   vg_[21] = {0,3,3,3,3,4,4,4,4,0,0,0,0,1,1,1,1,2,2,2,2};
  const float vw_[21] = {0.1f,0.1f,0.2f,0.3f,0.4f,0.1f,0.2f,0.3f,0.4f,
                         0.1f,0.2f,0.2f,0.4f,0.1f,0.2f,0.3f,0.4f,0.1f,0.2f,0.3f,0.4f};

  // --- per-joint conv(k5,p2)+elu, group-weighted accumulate into aggp ---
  {
    int o = tid >> 3, q = tid & 7;                 // o<32, ts = q*5+j
    for(int v = 0; v < NV; ++v){
      for(int idx = tid; idx < 42 * 16; idx += 256){
        int ts = idx >> 4, i = idx & 15; int t = t0 - 5 + ts;
        ystp[ts * 17 + i] = (t >= 0 && t < TM1) ? y1[((size_t)b * TM1 + t) * HH + v * 16 + i] : 0.f;
      }
      __syncthreads();
      int g = vg_[v]; float wv = vw_[v];
      const float* wp = W2 + v * 2560 + o * 80;
      float acc5[5];
      float bias = b2[v * 32 + o];
#pragma unroll
      for(int j = 0; j < 5; ++j) acc5[j] = bias;
#pragma unroll
      for(int i = 0; i < 16; ++i){
        float w0 = wp[i*5+0], w1 = wp[i*5+1], w2v = wp[i*5+2], w3v = wp[i*5+3], w4v = wp[i*5+4];
#pragma unroll
        for(int j = 0; j < 5; ++j){
          int ts = q * 5 + j;
          if(ts < 38){
            acc5[j] += w0*ystp[ts*17+i] + w1*ystp[(ts+1)*17+i] + w2v*ystp[(ts+2)*17+i]
                     + w3v*ystp[(ts+3)*17+i] + w4v*ystp[(ts+4)*17+i];
          }
        }
      }
#pragma unroll
      for(int j = 0; j < 5; ++j){
        int ts = q * 5 + j;
        if(ts < 38){
          int t = t0 - 3 + ts;
          if(t >= 0 && t < TM1) aggp[(g * 32 + o) * 38 + ts] += wv * elu_f(acc5[j]);
        }
      }
      __syncthreads();
    }
  }

  // --- 5x group conv(k3,p1)+elu, weighted sum into zinp ---
  {
    int c = tid >> 2, q = tid & 3;                 // c<64, ts = q*9+j (36)
    for(int k5 = 0; k5 < 5; ++k5){
      float coef = (k5 == 0) ? 0.12f : 0.22f;
      const float* wp = W3 + k5 * 6144 + c * 96;
      float accv[9];
      float bias = b3[k5 * 64 + c];
#pragma unroll
      for(int j = 0; j < 9; ++j) accv[j] = bias;
      for(int i = 0; i < 32; ++i){
        float w0 = wp[i*3+0], w1 = wp[i*3+1], w2v = wp[i*3+2];
        const float* ap = &aggp[(k5 * 32 + i) * 38 + q * 9];
#pragma unroll
        for(int j = 0; j < 9; ++j)
          accv[j] += w0*ap[j] + w1*ap[j+1] + w2v*ap[j+2];
      }
      __syncthreads();
#pragma unroll
      for(int j = 0; j < 9; ++j){
        int ts = q * 9 + j;
        int t = t0 - 2 + ts;
        if(t >= 0 && t < TM1) zinp[c * 36 + ts] += coef * elu_f(accv[j]);
      }
      __syncthreads();
    }
  }

  // --- conv(k3,p1)+elu -> z (zzp) ---
  {
    int c = tid >> 2, q = tid & 3;                 // ts = q*9+j, guard <34
    const float* wp = W3z + c * 192;
    float accv[9];
    float bias = b3z[c];
#pragma unroll
    for(int j = 0; j < 9; ++j) accv[j] = bias;
    for(int i = 0; i < 64; ++i){
      float w0 = wp[i*3+0], w1 = wp[i*3+1], w2v = wp[i*3+2];
      const float* zp = &zinp[i * 36 + q * 9];
#pragma unroll
      for(int j = 0; j < 9; ++j)
        accv[j] += w0*zp[j] + w1*zp[j+1] + w2v*zp[j+2];
    }
    __syncthreads();
#pragma unroll
    for(int j = 0; j < 9; ++j){
      int ts = q * 9 + j;
      if(ts < 34){
        int t = t0 - 1 + ts;
        zzp[c * 34 + ts] = (t >= 0 && t < TM1) ? elu_f(accv[j]) : 0.f;
      }
    }
    __syncthreads();
  }

  // --- affs conv(k3,p1)+elu (output, transposed) ---
  if(tid < 128){
    int a = tid >> 5, tt = tid & 31;
    const float* wp = Wza + a * 192;
    float acc = bza[a];
    for(int i = 0; i < 64; ++i){
      const float* zp = &zzp[i * 34 + tt];
      acc += wp[i*3+0]*zp[0] + wp[i*3+1]*zp[1] + wp[i*3+2]*zp[2];
    }
    float av = elu_f(acc);
    affp[a * 32 + tt] = av;
    int t = t0 + tt;
    if(t < TM1) out_affs[((size_t)b * TM1 + t) * 4 + a] = av;
  }
  __syncthreads();

  // --- lbl1 = elu(W4 . affs + b4) -> lblA[128][32] (overwrites zin/zz) ---
  for(int idx = tid; idx < 4096; idx += 256){
    int d = idx >> 5, tt = idx & 31;
    float acc = b4[d] + W4[d*4+0]*affp[tt] + W4[d*4+1]*affp[32+tt]
              + W4[d*4+2]*affp[64+tt] + W4[d*4+3]*affp[96+tt];
    lblA[idx] = elu_f(acc);
  }
  __syncthreads();

  // --- lbl2 = elu(W5 . lbl1 + b5); BN over t; logits; sigmoid ---
  {
    int tt = tid >> 3, dg = tid & 7;               // d = dg*16+dd
    float l2[16];
#pragma unroll
    for(int dd = 0; dd < 16; ++dd) l2[dd] = b5[dg * 16 + dd];
    for(int cc = 0; cc < 128; ++cc){
      float xv = lblA[cc * 32 + tt];
#pragma unroll
      for(int dd = 0; dd < 16; ++dd)
        l2[dd] += W5[(dg * 16 + dd) * 128 + cc] * xv;
    }
    int t = t0 + tt;
    float sc = 0.f, bb = 0.f;
    if(t < TM1){ sc = gmm[t] * rsqrtf(1.f + 1e-5f); bb = bet[t]; }
    float lg[4] = {0.f, 0.f, 0.f, 0.f};
#pragma unroll
    for(int dd = 0; dd < 16; ++dd){
      int d = dg * 16 + dd;
      float val = elu_f(l2[dd]) * sc + bb;
#pragma unroll
      for(int c = 0; c < 4; ++c) lg[c] += Wc[c * 128 + d] * val;
    }
    __syncthreads();
#pragma unroll
    for(int c = 0; c < 4; ++c) lgpp[(tt * 8 + dg) * 4 + c] = lg[c];
  }
  __syncthreads();
  if(tid < 128){
    int tt = tid >> 2, c = tid & 3;
    float s = bc[c];
#pragma unroll
    for(int dg = 0; dg < 8; ++dg) s += lgpp[(tt * 8 + dg) * 4 + c];
    int ta = t0 + tt;
    if(ta < TM1) out_lab[((size_t)b * TM1 + ta) * 4 + c] = sigm_f(s);
  }
}

extern "C" void kernel_launch(void* const* d_in, const int* in_sizes, int n_in,
                              void* d_out, int out_size, void* d_ws, size_t ws_size,
                              hipStream_t stream){
  (void)in_sizes; (void)n_in; (void)out_size; (void)ws_size;
  const float* x_diffs = (const float*)d_in[1];
  const float* h_init  = (const float*)d_in[3];
  const float* Wih0 = (const float*)d_in[4];
  const float* Whh0 = (const float*)d_in[5];
  const float* bih0 = (const float*)d_in[6];
  const float* bhh0 = (const float*)d_in[7];
  const float* Wih1 = (const float*)d_in[8];
  const float* Whh1 = (const float*)d_in[9];
  const float* bih1 = (const float*)d_in[10];
  const float* bhh1 = (const float*)d_in[11];
  const float* W2  = (const float*)d_in[12];
  const float* b2  = (const float*)d_in[13];
  const float* W3  = (const float*)d_in[14];
  const float* b3  = (const float*)d_in[15];
  const float* W3z = (const float*)d_in[16];
  const float* b3z = (const float*)d_in[17];
  const float* Wza = (const float*)d_in[18];
  const float* bza = (const float*)d_in[19];
  const float* W4  = (const float*)d_in[20];
  const float* b4  = (const float*)d_in[21];
  const float* W5  = (const float*)d_in[22];
  const float* b5  = (const float*)d_in[23];
  const float* gmm = (const float*)d_in[24];
  const float* bet = (const float*)d_in[25];
  const float* Wc  = (const float*)d_in[26];
  const float* bc  = (const float*)d_in[27];
  float* out = (float*)d_out;

  // workspace layout (floats): ~116 MB total
  float* ws   = (float*)d_ws;
  float* x_ws = ws;                       // 32*63*2047      = 4,126,752
  float* y1   = x_ws + 4126752;           // 32*2047*336     = 22,009,344
  float* y0r  = y1 + 22009344;            // 32*RING*336     =  2,752,512
  float* hb   = y0r + 2752512;            // 4*32*336        =     43,008
  int*   flg  = (int*)(hb + 43008);       // 2 * 16 * GU * FLG_STRIDE ints

  float* h0b = hb;                        // two buffers: hb, hb + NB*HH
  float* h1b = hb + 2 * NB * HH;

  float* out_affs = out;
  float* out_lab  = out + (size_t)NB * TM1 * 4;
  float* hT0 = out + 2 * (size_t)NB * TM1 * 4;
  float* hT1 = hT0 + NB * HH;

  (void)hipMemsetAsync(flg, 0, 2 * 16 * GU * FLG_STRIDE * sizeof(int), stream);
  (void)hipMemcpyAsync(h0b, h_init,           NB * HH * sizeof(float), hipMemcpyDeviceToDevice, stream);
  (void)hipMemcpyAsync(h1b, h_init + NB * HH, NB * HH * sizeof(float), hipMemcpyDeviceToDevice, stream);

  k_euler<<<dim3(NB * NV), 256, 0, stream>>>(x_diffs, x_ws);

  k_fused<<<dim3(256), SCAN_T, 0, stream>>>(
      Whh0, bhh0, Wih0, bih0, Whh1, bhh1, Wih1, bih1, x_ws,
      h0b, h1b, y0r, y1, hT0, hT1,
      flg, flg + 16 * GU * FLG_STRIDE);

  k_head<<<dim3(64, NB), 256, 0, stream>>>(y1, W2, b2, W3, b3, W3z, b3z, Wza, bza,
                                           W4, b4, W5, b5, gmm, bet, Wc, bc,
                                           out_affs, out_lab);
}

// Round 10
// 17899.664 us; speedup vs baseline: 1.0211x; 1.0021x over previous
//
#include <hip/hip_runtime.h>
#include <math.h>

#define TM1 2047
#define NB 32
#define NV 21
#define HH 336
#define G3 1008
#define FLG_STRIDE 32   // ints per flag slot (128B)
#define GU 8
#define UU 42
#define SCAN_T 512
#define RING 256        // y0 ring depth (power of 2)

__device__ __forceinline__ float elu_f(float x){ return x > 0.f ? x : (expf(x) - 1.f); }
__device__ __forceinline__ float sigm_f(float x){ return 1.f / (1.f + expf(-x)); }

// ---------------- quaternion -> euler (zyx) + time-normalize ----------------
__global__ __launch_bounds__(256) void k_euler(const float* __restrict__ xd, float* __restrict__ xout){
  int b = blockIdx.x / NV, v = blockIdx.x % NV;
  const float* q = xd + ((size_t)b * 84 + 4 * v) * TM1;
  float ex[8], ey[8], ez[8];
  float sx = 0.f, sy = 0.f, sz = 0.f;
#pragma unroll
  for(int it = 0; it < 8; ++it){
    int t = threadIdx.x + it * 256;
    float e0 = 0.f, e1 = 0.f, e2 = 0.f;
    if(t < TM1){
      float q0 = q[t], q1 = q[TM1 + t], q2 = q[2 * TM1 + t], q3 = q[3 * TM1 + t];
      e0 = atan2f(2.f * (q0 * q1 - q2 * q3), 1.f - 2.f * (q1 * q1 + q2 * q2));
      float s = 2.f * (q1 * q3 + q0 * q2);
      s = fminf(1.f, fmaxf(-1.f, s));
      e1 = asinf(s);
      e2 = atan2f(2.f * (q0 * q3 - q1 * q2), 1.f - 2.f * (q2 * q2 + q3 * q3));
    }
    ex[it] = e0; ey[it] = e1; ez[it] = e2;
    sx += e0 * e0; sy += e1 * e1; sz += e2 * e2;
  }
  __shared__ float rb[3][256];
  rb[0][threadIdx.x] = sx; rb[1][threadIdx.x] = sy; rb[2][threadIdx.x] = sz;
  __syncthreads();
  if(threadIdx.x < 3){
    float s = 0.f;
    for(int i = 0; i < 256; ++i) s += rb[threadIdx.x][i];
    rb[threadIdx.x][0] = 1.f / fmaxf(sqrtf(s), 1e-12f);
  }
  __syncthreads();
  float i0 = rb[0][0], i1 = rb[1][0], i2 = rb[2][0];
  float* xo = xout + ((size_t)b * 63 + 3 * v) * TM1;
#pragma unroll
  for(int it = 0; it < 8; ++it){
    int t = threadIdx.x + it * 256;
    if(t < TM1){
      xo[t]            = ex[it] * i0;
      xo[TM1 + t]      = ey[it] * i1;
      xo[2 * TM1 + t]  = ez[it] * i2;
    }
  }
}

// ---------------- fused 2-layer persistent GRU scan ----------------
// 256 WGs: blocks 0..127 = layer 0, 128..255 = layer 1 (concurrent, L1 trails).
// Per layer: 8 unit-slices (42 units) x 16 batch-pairs. Whh (+Wih) in VGPRs.
// amdgpu_waves_per_eu(1,2): max 2 waves/EU -> 256-VGPR pressure budget. REQUIRED:
// L1 holds wh[84]+wx[84]=168 weight VGPRs/thread. __launch_bounds__(512,2) (min
// only) left the allocator targeting 4 waves/EU -> 128 VGPR cap -> per-step
// scratch spills (r8/r9: VGPR_Count=128, WRITE_SIZE 464MB of scratch leakage).
// Sync: per-WG flags (128B apart), relaxed agent-scope atomics (LLC-coherent).
// y0 ring with backpressure: L0 step t waits flag1 >= t-RING+1 before reusing slot.
__global__ __attribute__((amdgpu_flat_work_group_size(512, 512), amdgpu_waves_per_eu(1, 2)))
void k_fused(
    const float* __restrict__ Whh0, const float* __restrict__ bhh0,
    const float* __restrict__ Wih0, const float* __restrict__ bih0,
    const float* __restrict__ Whh1, const float* __restrict__ bhh1,
    const float* __restrict__ Wih1, const float* __restrict__ bih1,
    const float* __restrict__ x_ws,
    float* h0b, float* h1b, float* y0r, float* __restrict__ y1,
    float* hT0, float* hT1, int* flg0, int* flg1){
  int lay = blockIdx.x >> 7;
  int idx = blockIdx.x & 127;
  int ug = idx >> 4, pr = idx & 15;
  int u0 = ug * UU, b0 = pr * 2;
  int tid = threadIdx.x;
  int* f0 = flg0 + pr * (GU * FLG_STRIDE);
  int* f1 = flg1 + pr * (GU * FLG_STRIDE);
  __shared__ float hl[2][HH];
  __shared__ float yl[2][HH];           // L1: y0[t]; L0: x[t] (63 ch, slot 63 zeroed)
  __shared__ float part_h[3*UU][4][2];
  __shared__ float part_x[3*UU][4][2];

  int r = tid >> 2, kq = tid & 3;
  bool act = (tid < 3 * UU * 4);        // 504
  bool comb = (tid < 2 * UU);           // 84
  int cu = tid % UU, cb = tid / UU;

  if(lay == 0){
    // ---------- layer 0 ----------
    float wh[84], wx[16];
    if(act){
      int rglob = (r / UU) * HH + u0 + (r % UU);
      const float* wp = Whh0 + (size_t)rglob * HH + kq * 84;
#pragma unroll
      for(int j = 0; j < 84; ++j) wh[j] = wp[j];
      int k0 = kq * 16;
      int xlen = 63 - k0; if(xlen > 16) xlen = 16;
      const float* wq = Wih0 + (size_t)rglob * 63 + k0;
#pragma unroll
      for(int j = 0; j < 16; ++j) wx[j] = (j < xlen) ? wq[j] : 0.f;
    }
    float bh_r=0.f,bh_z=0.f,bh_n=0.f,bx_r=0.f,bx_z=0.f,bx_n=0.f;
    if(comb){
      bh_r = bhh0[u0+cu]; bh_z = bhh0[HH+u0+cu]; bh_n = bhh0[2*HH+u0+cu];
      bx_r = bih0[u0+cu]; bx_z = bih0[HH+u0+cu]; bx_n = bih0[2*HH+u0+cu];
    }
    bool xload = (tid >= 384 && tid < 510);
    int xq = tid - 384, xcb = xq / 63, xch = xq - xcb * 63;
    const float* xbase = x_ws + ((size_t)(b0 + xcb) * 63 + xch) * TM1;
    if(tid == 510){ yl[0][63] = 0.f; yl[1][63] = 0.f; }   // pad slot for kq=3 tail
    for(int t = 0; t < TM1; ++t){
      float xr = 0.f;
      if(xload) xr = xbase[t];          // immutable: prefetch before spin, hides latency
      if(t > 0 && tid < GU){            // peer h0 ready?
        while(__hip_atomic_load(f0 + tid*FLG_STRIDE, __ATOMIC_RELAXED, __HIP_MEMORY_SCOPE_AGENT) < t)
          __builtin_amdgcn_s_sleep(1);
      }
      if(t >= RING && tid >= 64 && tid < 64 + GU){   // ring slot consumed by L1?
        while(__hip_atomic_load(f1 + (tid-64)*FLG_STRIDE, __ATOMIC_RELAXED, __HIP_MEMORY_SCOPE_AGENT) < t - RING + 1)
          __builtin_amdgcn_s_sleep(1);
      }
      __syncthreads();
      float* hcur = h0b + (size_t)(t & 1) * NB * HH;
      float* hnxt = h0b + (size_t)((t + 1) & 1) * NB * HH;
      for(int i2 = tid; i2 < 2*HH; i2 += SCAN_T){
        int bs = (i2 >= HH), k = i2 - bs*HH;
        hl[bs][k] = __hip_atomic_load(&hcur[(size_t)(b0+bs)*HH + k],
                                      __ATOMIC_RELAXED, __HIP_MEMORY_SCOPE_AGENT);
      }
      if(xload) yl[xcb][xch] = xr;
      __syncthreads();
      if(act){
        float a0 = 0.f, a1 = 0.f;
#pragma unroll
        for(int jj = 0; jj < 21; ++jj){
          float4 h0 = *(const float4*)&hl[0][kq*84 + jj*4];
          float4 h1 = *(const float4*)&hl[1][kq*84 + jj*4];
          a0 += wh[jj*4+0]*h0.x + wh[jj*4+1]*h0.y + wh[jj*4+2]*h0.z + wh[jj*4+3]*h0.w;
          a1 += wh[jj*4+0]*h1.x + wh[jj*4+1]*h1.y + wh[jj*4+2]*h1.z + wh[jj*4+3]*h1.w;
        }
        part_h[r][kq][0] = a0; part_h[r][kq][1] = a1;
        float c0 = 0.f, c1 = 0.f;
        int k0 = kq * 16;
#pragma unroll
        for(int j = 0; j < 16; ++j){
          c0 += wx[j] * yl[0][k0 + j];
          c1 += wx[j] * yl[1][k0 + j];
        }
        part_x[r][kq][0] = c0; part_x[r][kq][1] = c1;
      }
      __syncthreads();
      float hnew = 0.f;
      if(comb){
        float ghr = part_h[cu][0][cb]+part_h[cu][1][cb]+part_h[cu][2][cb]+part_h[cu][3][cb] + bh_r;
        float gxr = part_x[cu][0][cb]+part_x[cu][1][cb]+part_x[cu][2][cb]+part_x[cu][3][cb] + bx_r;
        float ghz = part_h[UU+cu][0][cb]+part_h[UU+cu][1][cb]+part_h[UU+cu][2][cb]+part_h[UU+cu][3][cb] + bh_z;
        float gxz = part_x[UU+cu][0][cb]+part_x[UU+cu][1][cb]+part_x[UU+cu][2][cb]+part_x[UU+cu][3][cb] + bx_z;
        float ghn = part_h[2*UU+cu][0][cb]+part_h[2*UU+cu][1][cb]+part_h[2*UU+cu][2][cb]+part_h[2*UU+cu][3][cb] + bh_n;
        float gxn = part_x[2*UU+cu][0][cb]+part_x[2*UU+cu][1][cb]+part_x[2*UU+cu][2][cb]+part_x[2*UU+cu][3][cb] + bx_n;
        float rg = sigm_f(gxr + ghr);
        float zg = sigm_f(gxz + ghz);
        float ng = tanhf(gxn + rg * ghn);
        hnew = (1.f - zg) * ng + zg * hl[cb][u0 + cu];
        __hip_atomic_store(&hnxt[(size_t)(b0+cb)*HH + u0+cu], hnew,
                           __ATOMIC_RELAXED, __HIP_MEMORY_SCOPE_AGENT);
        __hip_atomic_store(&y0r[((size_t)(b0+cb)*RING + (t & (RING-1)))*HH + u0+cu], hnew,
                           __ATOMIC_RELAXED, __HIP_MEMORY_SCOPE_AGENT);
      }
      __syncthreads();                  // vmcnt(0): h + ring stores acked at LLC
      if(tid == 0)
        __hip_atomic_store(f0 + ug*FLG_STRIDE, t + 1,
                           __ATOMIC_RELAXED, __HIP_MEMORY_SCOPE_AGENT);
      if(comb && t == TM1-1) hT0[(size_t)(b0+cb)*HH + u0+cu] = hnew;
    }
  } else {
    // ---------- layer 1 (trails layer 0) ----------
    float wh[84], wx[84];
    if(act){
      int rglob = (r / UU) * HH + u0 + (r % UU);
      const float* wp = Whh1 + (size_t)rglob * HH + kq * 84;
      const float* wq = Wih1 + (size_t)rglob * HH + kq * 84;
#pragma unroll
      for(int j = 0; j < 84; ++j){ wh[j] = wp[j]; wx[j] = wq[j]; }
    }
    float bh_r=0.f,bh_z=0.f,bh_n=0.f,bx_r=0.f,bx_z=0.f,bx_n=0.f;
    if(comb){
      bh_r = bhh1[u0+cu]; bh_z = bhh1[HH+u0+cu]; bh_n = bhh1[2*HH+u0+cu];
      bx_r = bih1[u0+cu]; bx_z = bih1[HH+u0+cu]; bx_n = bih1[2*HH+u0+cu];
    }
    for(int t = 0; t < TM1; ++t){
      if(tid < GU){                     // y0[t] ready? (L0 finished step t)
        while(__hip_atomic_load(f0 + tid*FLG_STRIDE, __ATOMIC_RELAXED, __HIP_MEMORY_SCOPE_AGENT) < t + 1)
          __builtin_amdgcn_s_sleep(1);
      }
      if(t > 0 && tid >= 64 && tid < 64 + GU){       // peer h1 ready?
        while(__hip_atomic_load(f1 + (tid-64)*FLG_STRIDE, __ATOMIC_RELAXED, __HIP_MEMORY_SCOPE_AGENT) < t)
          __builtin_amdgcn_s_sleep(1);
      }
      __syncthreads();
      float* hcur = h1b + (size_t)(t & 1) * NB * HH;
      float* hnxt = h1b + (size_t)((t + 1) & 1) * NB * HH;
      for(int i2 = tid; i2 < 2*HH; i2 += SCAN_T){
        int bs = (i2 >= HH), k = i2 - bs*HH;
        hl[bs][k] = __hip_atomic_load(&hcur[(size_t)(b0+bs)*HH + k],
                                      __ATOMIC_RELAXED, __HIP_MEMORY_SCOPE_AGENT);
        yl[bs][k] = __hip_atomic_load(&y0r[((size_t)(b0+bs)*RING + (t & (RING-1)))*HH + k],
                                      __ATOMIC_RELAXED, __HIP_MEMORY_SCOPE_AGENT);
      }
      __syncthreads();
      if(act){
        float a0=0.f, a1=0.f, c0=0.f, c1=0.f;
#pragma unroll
        for(int jj = 0; jj < 21; ++jj){
          float4 h0 = *(const float4*)&hl[0][kq*84 + jj*4];
          float4 h1 = *(const float4*)&hl[1][kq*84 + jj*4];
          float4 y0v = *(const float4*)&yl[0][kq*84 + jj*4];
          float4 y1v = *(const float4*)&yl[1][kq*84 + jj*4];
          float w0 = wh[jj*4+0], w1 = wh[jj*4+1], w2 = wh[jj*4+2], w3 = wh[jj*4+3];
          a0 += w0*h0.x + w1*h0.y + w2*h0.z + w3*h0.w;
          a1 += w0*h1.x + w1*h1.y + w2*h1.z + w3*h1.w;
          float v0 = wx[jj*4+0], v1 = wx[jj*4+1], v2 = wx[jj*4+2], v3 = wx[jj*4+3];
          c0 += v0*y0v.x + v1*y0v.y + v2*y0v.z + v3*y0v.w;
          c1 += v0*y1v.x + v1*y1v.y + v2*y1v.z + v3*y1v.w;
        }
        part_h[r][kq][0] = a0; part_h[r][kq][1] = a1;
        part_x[r][kq][0] = c0; part_x[r][kq][1] = c1;
      }
      __syncthreads();
      float hnew = 0.f;
      if(comb){
        float ghr = part_h[cu][0][cb]+part_h[cu][1][cb]+part_h[cu][2][cb]+part_h[cu][3][cb] + bh_r;
        float gxr = part_x[cu][0][cb]+part_x[cu][1][cb]+part_x[cu][2][cb]+part_x[cu][3][cb] + bx_r;
        float ghz = part_h[UU+cu][0][cb]+part_h[UU+cu][1][cb]+part_h[UU+cu][2][cb]+part_h[UU+cu][3][cb] + bh_z;
        float gxz = part_x[UU+cu][0][cb]+part_x[UU+cu][1][cb]+part_x[UU+cu][2][cb]+part_x[UU+cu][3][cb] + bx_z;
        float ghn = part_h[2*UU+cu][0][cb]+part_h[2*UU+cu][1][cb]+part_h[2*UU+cu][2][cb]+part_h[2*UU+cu][3][cb] + bh_n;
        float gxn = part_x[2*UU+cu][0][cb]+part_x[2*UU+cu][1][cb]+part_x[2*UU+cu][2][cb]+part_x[2*UU+cu][3][cb] + bx_n;
        float rg = sigm_f(gxr + ghr);
        float zg = sigm_f(gxz + ghz);
        float ng = tanhf(gxn + rg * ghn);
        hnew = (1.f - zg) * ng + zg * hl[cb][u0 + cu];
        __hip_atomic_store(&hnxt[(size_t)(b0+cb)*HH + u0+cu], hnew,
                           __ATOMIC_RELAXED, __HIP_MEMORY_SCOPE_AGENT);
      }
      __syncthreads();                  // vmcnt(0): h store acked at LLC
      if(tid == 0)
        __hip_atomic_store(f1 + ug*FLG_STRIDE, t + 1,
                           __ATOMIC_RELAXED, __HIP_MEMORY_SCOPE_AGENT);
      if(comb){                         // off critical path (drains during next spin)
        y1[((size_t)(b0+cb)*TM1 + t)*HH + u0+cu] = hnew;
        if(t == TM1-1) hT1[(size_t)(b0+cb)*HH + u0+cu] = hnew;
      }
    }
  }
}

// ---------------- fused conv stack + dense head (32-t tile, static LDS 45.6KB) ----------------
__global__ __launch_bounds__(256) void k_head(const float* __restrict__ y1,
   const float* __restrict__ W2, const float* __restrict__ b2,
   const float* __restrict__ W3, const float* __restrict__ b3,
   const float* __restrict__ W3z, const float* __restrict__ b3z,
   const float* __restrict__ Wza, const float* __restrict__ bza,
   const float* __restrict__ W4, const float* __restrict__ b4,
   const float* __restrict__ W5, const float* __restrict__ b5,
   const float* __restrict__ gmm, const float* __restrict__ bet,
   const float* __restrict__ Wc, const float* __restrict__ bc,
   float* __restrict__ out_affs, float* __restrict__ out_lab){
  __shared__ float sm[11402];
  float* aggp = sm;             // [5*32][38]  6080
  float* zinp = sm + 6080;      // [64][36]    2304
  float* zzp  = sm + 8384;      // [64][34]    2176 -> ends 10560
  float* ystp = sm + 10560;     // [42][17]    714  -> ends 11274
  float* affp = sm + 11274;     // [4][32]     128  -> ends 11402
  float* lblA = sm + 6080;      // [128][32]   4096 (aliases zin+zz, dead by then)
  float* lgpp = sm;             // [32][8][4]  1024 (aliases aggp, dead by then)
  int t0 = blockIdx.x * 32;
  int b  = blockIdx.y;
  int tid = threadIdx.x;

  for(int i = tid; i < 6080; i += 256) aggp[i] = 0.f;
  for(int i = tid; i < 2304; i += 256) zinp[i] = 0.f;
  __syncthreads();

  const int   vg_[21] = {0,3,3,3,3,4,4,4,4,0,0,0,0,1,1,1,1,2,2,2,2};
  const float vw_[21] = {0.1f,0.1f,0.2f,0.3f,0.4f,0.1f,0.2f,0.3f,0.4f,
                         0.1f,0.2f,0.2f,0.4f,0.1f,0.2f,0.3f,0.4f,0.1f,0.2f,0.3f,0.4f};

  // --- per-joint conv(k5,p2)+elu, group-weighted accumulate into aggp ---
  {
    int o = tid >> 3, q = tid & 7;                 // o<32, ts = q*5+j
    for(int v = 0; v < NV; ++v){
      for(int idx = tid; idx < 42 * 16; idx += 256){
        int ts = idx >> 4, i = idx & 15; int t = t0 - 5 + ts;
        ystp[ts * 17 + i] = (t >= 0 && t < TM1) ? y1[((size_t)b * TM1 + t) * HH + v * 16 + i] : 0.f;
      }
      __syncthreads();
      int g = vg_[v]; float wv = vw_[v];
      const float* wp = W2 + v * 2560 + o * 80;
      float acc5[5];
      float bias = b2[v * 32 + o];
#pragma unroll
      for(int j = 0; j < 5; ++j) acc5[j] = bias;
#pragma unroll
      for(int i = 0; i < 16; ++i){
        float w0 = wp[i*5+0], w1 = wp[i*5+1], w2v = wp[i*5+2], w3v = wp[i*5+3], w4v = wp[i*5+4];
#pragma unroll
        for(int j = 0; j < 5; ++j){
          int ts = q * 5 + j;
          if(ts < 38){
            acc5[j] += w0*ystp[ts*17+i] + w1*ystp[(ts+1)*17+i] + w2v*ystp[(ts+2)*17+i]
                     + w3v*ystp[(ts+3)*17+i] + w4v*ystp[(ts+4)*17+i];
          }
        }
      }
#pragma unroll
      for(int j = 0; j < 5; ++j){
        int ts = q * 5 + j;
        if(ts < 38){
          int t = t0 - 3 + ts;
          if(t >= 0 && t < TM1) aggp[(g * 32 + o) * 38 + ts] += wv * elu_f(acc5[j]);
        }
      }
      __syncthreads();
    }
  }

  // --- 5x group conv(k3,p1)+elu, weighted sum into zinp ---
  {
    int c = tid >> 2, q = tid & 3;                 // c<64, ts = q*9+j (36)
    for(int k5 = 0; k5 < 5; ++k5){
      float coef = (k5 == 0) ? 0.12f : 0.22f;
      const float* wp = W3 + k5 * 6144 + c * 96;
      float accv[9];
      float bias = b3[k5 * 64 + c];
#pragma unroll
      for(int j = 0; j < 9; ++j) accv[j] = bias;
      for(int i = 0; i < 32; ++i){
        float w0 = wp[i*3+0], w1 = wp[i*3+1], w2v = wp[i*3+2];
        const float* ap = &aggp[(k5 * 32 + i) * 38 + q * 9];
#pragma unroll
        for(int j = 0; j < 9; ++j)
          accv[j] += w0*ap[j] + w1*ap[j+1] + w2v*ap[j+2];
      }
      __syncthreads();
#pragma unroll
      for(int j = 0; j < 9; ++j){
        int ts = q * 9 + j;
        int t = t0 - 2 + ts;
        if(t >= 0 && t < TM1) zinp[c * 36 + ts] += coef * elu_f(accv[j]);
      }
      __syncthreads();
    }
  }

  // --- conv(k3,p1)+elu -> z (zzp) ---
  {
    int c = tid >> 2, q = tid & 3;                 // ts = q*9+j, guard <34
    const float* wp = W3z + c * 192;
    float accv[9];
    float bias = b3z[c];
#pragma unroll
    for(int j = 0; j < 9; ++j) accv[j] = bias;
    for(int i = 0; i < 64; ++i){
      float w0 = wp[i*3+0], w1 = wp[i*3+1], w2v = wp[i*3+2];
      const float* zp = &zinp[i * 36 + q * 9];
#pragma unroll
      for(int j = 0; j < 9; ++j)
        accv[j] += w0*zp[j] + w1*zp[j+1] + w2v*zp[j+2];
    }
    __syncthreads();
#pragma unroll
    for(int j = 0; j < 9; ++j){
      int ts = q * 9 + j;
      if(ts < 34){
        int t = t0 - 1 + ts;
        zzp[c * 34 + ts] = (t >= 0 && t < TM1) ? elu_f(accv[j]) : 0.f;
      }
    }
    __syncthreads();
  }

  // --- affs conv(k3,p1)+elu (output, transposed) ---
  if(tid < 128){
    int a = tid >> 5, tt = tid & 31;
    const float* wp = Wza + a * 192;
    float acc = bza[a];
    for(int i = 0; i < 64; ++i){
      const float* zp = &zzp[i * 34 + tt];
      acc += wp[i*3+0]*zp[0] + wp[i*3+1]*zp[1] + wp[i*3+2]*zp[2];
    }
    float av = elu_f(acc);
    affp[a * 32 + tt] = av;
    int t = t0 + tt;
    if(t < TM1) out_affs[((size_t)b * TM1 + t) * 4 + a] = av;
  }
  __syncthreads();

  // --- lbl1 = elu(W4 . affs + b4) -> lblA[128][32] (overwrites zin/zz) ---
  for(int idx = tid; idx < 4096; idx += 256){
    int d = idx >> 5, tt = idx & 31;
    float acc = b4[d] + W4[d*4+0]*affp[tt] + W4[d*4+1]*affp[32+tt]
              + W4[d*4+2]*affp[64+tt] + W4[d*4+3]*affp[96+tt];
    lblA[idx] = elu_f(acc);
  }
  __syncthreads();

  // --- lbl2 = elu(W5 . lbl1 + b5); BN over t; logits; sigmoid ---
  {
    int tt = tid >> 3, dg = tid & 7;               // d = dg*16+dd
    float l2[16];
#pragma unroll
    for(int dd = 0; dd < 16; ++dd) l2[dd] = b5[dg * 16 + dd];
    for(int cc = 0; cc < 128; ++cc){
      float xv = lblA[cc * 32 + tt];
#pragma unroll
      for(int dd = 0; dd < 16; ++dd)
        l2[dd] += W5[(dg * 16 + dd) * 128 + cc] * xv;
    }
    int t = t0 + tt;
    float sc = 0.f, bb = 0.f;
    if(t < TM1){ sc = gmm[t] * rsqrtf(1.f + 1e-5f); bb = bet[t]; }
    float lg[4] = {0.f, 0.f, 0.f, 0.f};
#pragma unroll
    for(int dd = 0; dd < 16; ++dd){
      int d = dg * 16 + dd;
      float val = elu_f(l2[dd]) * sc + bb;
#pragma unroll
      for(int c = 0; c < 4; ++c) lg[c] += Wc[c * 128 + d] * val;
    }
    __syncthreads();
#pragma unroll
    for(int c = 0; c < 4; ++c) lgpp[(tt * 8 + dg) * 4 + c] = lg[c];
  }
  __syncthreads();
  if(tid < 128){
    int tt = tid >> 2, c = tid & 3;
    float s = bc[c];
#pragma unroll
    for(int dg = 0; dg < 8; ++dg) s += lgpp[(tt * 8 + dg) * 4 + c];
    int ta = t0 + tt;
    if(ta < TM1) out_lab[((size_t)b * TM1 + ta) * 4 + c] = sigm_f(s);
  }
}

extern "C" void kernel_launch(void* const* d_in, const int* in_sizes, int n_in,
                              void* d_out, int out_size, void* d_ws, size_t ws_size,
                              hipStream_t stream){
  (void)in_sizes; (void)n_in; (void)out_size; (void)ws_size;
  const float* x_diffs = (const float*)d_in[1];
  const float* h_init  = (const float*)d_in[3];
  const float* Wih0 = (const float*)d_in[4];
  const float* Whh0 = (const float*)d_in[5];
  const float* bih0 = (const float*)d_in[6];
  const float* bhh0 = (const float*)d_in[7];
  const float* Wih1 = (const float*)d_in[8];
  const float* Whh1 = (const float*)d_in[9];
  const float* bih1 = (const float*)d_in[10];
  const float* bhh1 = (const float*)d_in[11];
  const float* W2  = (const float*)d_in[12];
  const float* b2  = (const float*)d_in[13];
  const float* W3  = (const float*)d_in[14];
  const float* b3  = (const float*)d_in[15];
  const float* W3z = (const float*)d_in[16];
  const float* b3z = (const float*)d_in[17];
  const float* Wza = (const float*)d_in[18];
  const float* bza = (const float*)d_in[19];
  const float* W4  = (const float*)d_in[20];
  const float* b4  = (const float*)d_in[21];
  const float* W5  = (const float*)d_in[22];
  const float* b5  = (const float*)d_in[23];
  const float* gmm = (const float*)d_in[24];
  const float* bet = (const float*)d_in[25];
  const float* Wc  = (const float*)d_in[26];
  const float* bc  = (const float*)d_in[27];
  float* out = (float*)d_out;

  // workspace layout (floats): ~116 MB total
  float* ws   = (float*)d_ws;
  float* x_ws = ws;                       // 32*63*2047      = 4,126,752
  float* y1   = x_ws + 4126752;           // 32*2047*336     = 22,009,344
  float* y0r  = y1 + 22009344;            // 32*RING*336     =  2,752,512
  float* hb   = y0r + 2752512;            // 4*32*336        =     43,008
  int*   flg  = (int*)(hb + 43008);       // 2 * 16 * GU * FLG_STRIDE ints

  float* h0b = hb;                        // two buffers: hb, hb + NB*HH
  float* h1b = hb + 2 * NB * HH;

  float* out_affs = out;
  float* out_lab  = out + (size_t)NB * TM1 * 4;
  float* hT0 = out + 2 * (size_t)NB * TM1 * 4;
  float* hT1 = hT0 + NB * HH;

  (void)hipMemsetAsync(flg, 0, 2 * 16 * GU * FLG_STRIDE * sizeof(int), stream);
  (void)hipMemcpyAsync(h0b, h_init,           NB * HH * sizeof(float), hipMemcpyDeviceToDevice, stream);
  (void)hipMemcpyAsync(h1b, h_init + NB * HH, NB * HH * sizeof(float), hipMemcpyDeviceToDevice, stream);

  k_euler<<<dim3(NB * NV), 256, 0, stream>>>(x_diffs, x_ws);

  k_fused<<<dim3(256), SCAN_T, 0, stream>>>(
      Whh0, bhh0, Wih0, bih0, Whh1, bhh1, Wih1, bih1, x_ws,
      h0b, h1b, y0r, y1, hT0, hT1,
      flg, flg + 16 * GU * FLG_STRIDE);

  k_head<<<dim3(64, NB), 256, 0, stream>>>(y1, W2, b2, W3, b3, W3z, b3z, Wza, bza,
                                           W4, b4, W5, b5, gmm, bet, Wc, bc,
                                           out_affs, out_lab);
}

// Round 11
// 12972.815 us; speedup vs baseline: 1.4089x; 1.3798x over previous
//
#include <hip/hip_runtime.h>
#include <math.h>

#define TM1 2047
#define NB 32
#define NV 21
#define HH 336
#define FLG_STRIDE 32   // ints per flag slot (128B)
#define NG 8            // unit groups (42 units each)
#define NQ 8            // batch quads (4 batch each)
#define QB 4
#define UU 42
#define SCAN_T 512
#define RING 128        // ring depth (power of 2)

__device__ __forceinline__ float elu_f(float x){ return x > 0.f ? x : (expf(x) - 1.f); }
__device__ __forceinline__ float sigm_f(float x){ return 1.f / (1.f + expf(-x)); }

#define ALOAD(p)    __hip_atomic_load((p), __ATOMIC_RELAXED, __HIP_MEMORY_SCOPE_AGENT)
#define ASTORE(p,v) __hip_atomic_store((p), (v), __ATOMIC_RELAXED, __HIP_MEMORY_SCOPE_AGENT)

// ---------------- quaternion -> euler (zyx) + time-normalize ----------------
// out (TRANSPOSED): x_ws[b][t][63], channel = 3*v + c
__global__ __launch_bounds__(256) void k_euler(const float* __restrict__ xd, float* __restrict__ xout){
  int b = blockIdx.x / NV, v = blockIdx.x % NV;
  const float* q = xd + ((size_t)b * 84 + 4 * v) * TM1;
  float ex[8], ey[8], ez[8];
  float sx = 0.f, sy = 0.f, sz = 0.f;
#pragma unroll
  for(int it = 0; it < 8; ++it){
    int t = threadIdx.x + it * 256;
    float e0 = 0.f, e1 = 0.f, e2 = 0.f;
    if(t < TM1){
      float q0 = q[t], q1 = q[TM1 + t], q2 = q[2 * TM1 + t], q3 = q[3 * TM1 + t];
      e0 = atan2f(2.f * (q0 * q1 - q2 * q3), 1.f - 2.f * (q1 * q1 + q2 * q2));
      float s = 2.f * (q1 * q3 + q0 * q2);
      s = fminf(1.f, fmaxf(-1.f, s));
      e1 = asinf(s);
      e2 = atan2f(2.f * (q0 * q3 - q1 * q2), 1.f - 2.f * (q2 * q2 + q3 * q3));
    }
    ex[it] = e0; ey[it] = e1; ez[it] = e2;
    sx += e0 * e0; sy += e1 * e1; sz += e2 * e2;
  }
  __shared__ float rb[3][256];
  rb[0][threadIdx.x] = sx; rb[1][threadIdx.x] = sy; rb[2][threadIdx.x] = sz;
  __syncthreads();
  if(threadIdx.x < 3){
    float s = 0.f;
    for(int i = 0; i < 256; ++i) s += rb[threadIdx.x][i];
    rb[threadIdx.x][0] = 1.f / fmaxf(sqrtf(s), 1e-12f);
  }
  __syncthreads();
  float i0 = rb[0][0], i1 = rb[1][0], i2 = rb[2][0];
  float* xo = xout + (size_t)b * TM1 * 63 + 3 * v;
#pragma unroll
  for(int it = 0; it < 8; ++it){
    int t = threadIdx.x + it * 256;
    if(t < TM1){
      xo[(size_t)t * 63 + 0] = ex[it] * i0;
      xo[(size_t)t * 63 + 1] = ey[it] * i1;
      xo[(size_t)t * 63 + 2] = ez[it] * i2;
    }
  }
}

// ---------------- fused 3-stage persistent GRU pipeline ----------------
// 192 WGs: [0,64)=L0 recurrence, [64,128)=PROJ (gx1 = Wih1 . y0, off the serial
// path), [128,192)=L1 recurrence. Per stage: 8 unit/out groups x 8 batch-quads.
// EVERY branch holds <=84 weight floats/thread (the spill-free footprint proven
// in r7 at 116 VGPRs); L0's Wih0 slice lives in LDS (65-padded). Rings (128
// deep) decouple stages; relaxed agent-scope LLC atomics for all shared state.
__global__ __launch_bounds__(SCAN_T) void k_fused(
    const float* __restrict__ Whh0, const float* __restrict__ bhh0,
    const float* __restrict__ Wih0, const float* __restrict__ bih0,
    const float* __restrict__ Whh1, const float* __restrict__ bhh1,
    const float* __restrict__ Wih1, const float* __restrict__ bih1,
    const float* __restrict__ xws,
    float* h0b, float* h1b, float* y0r, float* gx1r, float* __restrict__ y1,
    float* hT0, float* hT1, int* flg0, int* flgP, int* flg1){
  const int stage = blockIdx.x >> 6;
  const int idx = blockIdx.x & 63;
  const int grp = idx >> 3, quad = idx & 7;
  const int u0 = grp * UU, b0 = quad * QB;
  const int tid = threadIdx.x;
  int* F0 = flg0 + (quad * NG) * FLG_STRIDE;
  int* FP = flgP + (quad * NG) * FLG_STRIDE;
  int* F1 = flg1 + (quad * NG) * FLG_STRIDE;

  __shared__ float vin[QB][HH];          // h (L0/L1) or y0 (PROJ)
  __shared__ float part[126][4][QB];     // [row][k-quarter][batch]
  __shared__ float part_xn[UU][4][QB];   // L0 n-gate x-部分
  __shared__ float wxl[126][65];         // L0: Wih0 slice (pad 65 -> conflict-free)
  __shared__ float xl[QB][64];           // L0: x[t]

  const int r = tid >> 2, kq = tid & 3;  // act decode (504 threads)
  const bool act = (tid < 504);
  const bool comb2 = (tid < 2 * UU * QB / 2); // 168: (cu,cb) for L0/L1 combine
  const int cu = tid >> 2, cb = tid & 3;

  if(stage == 0){
    // ================= L0: GRU layer 0 =================
    float wh[84];
    int gate = 0, uu = 0;
    if(act){
      gate = r / 42; uu = r - gate * 42;
      const float* wp = Whh0 + (size_t)(gate * HH + u0 + uu) * HH + kq * 84;
#pragma unroll
      for(int j = 0; j < 84; ++j) wh[j] = wp[j];
    }
    for(int i = tid; i < 126 * 63; i += SCAN_T){
      int rr = i / 63, cc = i - rr * 63; int g2 = rr / 42;
      wxl[rr][cc] = Wih0[(size_t)(g2 * HH + u0 + (rr - g2 * 42)) * 63 + cc];
    }
    for(int i = tid; i < 126; i += SCAN_T){ wxl[i][63] = 0.f; wxl[i][64] = 0.f; }
    if(tid < QB) xl[tid][63] = 0.f;
    float bsum_r=0.f, bsum_z=0.f, bh_n=0.f, bx_n=0.f;
    if(comb2){
      bsum_r = bhh0[u0+cu] + bih0[u0+cu];
      bsum_z = bhh0[HH+u0+cu] + bih0[HH+u0+cu];
      bh_n = bhh0[2*HH+u0+cu];
      bx_n = bih0[2*HH+u0+cu];
    }
    bool xload = (tid >= 256 && tid < 508);
    int xq = tid - 256, xcb = 0, xch = 0;
    const float* xbase = xws;
    if(xload){ xcb = xq / 63; xch = xq - xcb * 63;
               xbase = xws + ((size_t)(b0 + xcb) * TM1) * 63 + xch; }
    __syncthreads();
    float hnew = 0.f;
    for(int t = 0; t < TM1; ++t){
      float xr = 0.f;
      if(xload) xr = xbase[(size_t)t * 63];          // immutable, pre-spin prefetch
      if(t > 0 && tid < NG){
        while(ALOAD(F0 + tid * FLG_STRIDE) < t) __builtin_amdgcn_s_sleep(1);
      }
      if(t >= RING && tid >= 64 && tid < 64 + NG){   // y0 ring backpressure (PROJ)
        while(ALOAD(FP + (tid - 64) * FLG_STRIDE) < t - RING + 1) __builtin_amdgcn_s_sleep(1);
      }
      __syncthreads();
      float* hcur = h0b + (size_t)(t & 1) * NB * HH;
      float* hnxt = h0b + (size_t)((t + 1) & 1) * NB * HH;
      for(int i = tid; i < QB * HH; i += SCAN_T){
        int bs = i / HH, k = i - bs * HH;
        vin[bs][k] = ALOAD(&hcur[(size_t)(b0 + bs) * HH + k]);
      }
      if(xload) xl[xcb][xch] = xr;
      __syncthreads();
      if(act){
        float a0=0.f,a1=0.f,a2=0.f,a3=0.f;
#pragma unroll
        for(int jj = 0; jj < 21; ++jj){
          float4 h0 = *(const float4*)&vin[0][kq*84 + jj*4];
          float4 h1 = *(const float4*)&vin[1][kq*84 + jj*4];
          float4 h2 = *(const float4*)&vin[2][kq*84 + jj*4];
          float4 h3 = *(const float4*)&vin[3][kq*84 + jj*4];
          float w0=wh[jj*4+0], w1=wh[jj*4+1], w2=wh[jj*4+2], w3=wh[jj*4+3];
          a0 += w0*h0.x + w1*h0.y + w2*h0.z + w3*h0.w;
          a1 += w0*h1.x + w1*h1.y + w2*h1.z + w3*h1.w;
          a2 += w0*h2.x + w1*h2.y + w2*h2.z + w3*h2.w;
          a3 += w0*h3.x + w1*h3.y + w2*h3.z + w3*h3.w;
        }
        float c0=0.f,c1=0.f,c2=0.f,c3=0.f;
        int k0 = kq * 16;
#pragma unroll
        for(int j = 0; j < 16; ++j){
          float wv = wxl[r][k0 + j];
          c0 += wv * xl[0][k0 + j]; c1 += wv * xl[1][k0 + j];
          c2 += wv * xl[2][k0 + j]; c3 += wv * xl[3][k0 + j];
        }
        if(gate < 2){
          part[r][kq][0]=a0+c0; part[r][kq][1]=a1+c1; part[r][kq][2]=a2+c2; part[r][kq][3]=a3+c3;
        } else {
          part[r][kq][0]=a0; part[r][kq][1]=a1; part[r][kq][2]=a2; part[r][kq][3]=a3;
          part_xn[uu][kq][0]=c0; part_xn[uu][kq][1]=c1; part_xn[uu][kq][2]=c2; part_xn[uu][kq][3]=c3;
        }
      }
      __syncthreads();
      if(comb2){
        float ghr = part[cu][0][cb]+part[cu][1][cb]+part[cu][2][cb]+part[cu][3][cb] + bsum_r;
        float ghz = part[42+cu][0][cb]+part[42+cu][1][cb]+part[42+cu][2][cb]+part[42+cu][3][cb] + bsum_z;
        float ghn = part[84+cu][0][cb]+part[84+cu][1][cb]+part[84+cu][2][cb]+part[84+cu][3][cb] + bh_n;
        float gxn = part_xn[cu][0][cb]+part_xn[cu][1][cb]+part_xn[cu][2][cb]+part_xn[cu][3][cb] + bx_n;
        float rg = sigm_f(ghr), zg = sigm_f(ghz);
        float ng = tanhf(gxn + rg * ghn);
        hnew = (1.f - zg) * ng + zg * vin[cb][u0 + cu];
        ASTORE(&hnxt[(size_t)(b0+cb)*HH + u0+cu], hnew);
        ASTORE(&y0r[((size_t)(b0+cb)*RING + (t & (RING-1)))*HH + u0+cu], hnew);
      }
      __syncthreads();                   // vmcnt(0): stores acked at LLC
      if(tid == 0) ASTORE(F0 + grp * FLG_STRIDE, t + 1);
      if(comb2 && t == TM1-1) hT0[(size_t)(b0+cb)*HH + u0+cu] = hnew;
    }
  } else if(stage == 1){
    // ================= PROJ: gx1[t] = Wih1 . y0[t] + bih1 =================
    float wp_[84];
    float bias = 0.f;
    if(act){
      int gate = r / 42, uu = r - gate * 42;
      int rowg = gate * HH + grp * 42 + uu;
      const float* wq = Wih1 + (size_t)rowg * HH + kq * 84;
#pragma unroll
      for(int j = 0; j < 84; ++j) wp_[j] = wq[j];
      bias = bih1[rowg];
    }
    __syncthreads();
    for(int t = 0; t < TM1; ++t){
      if(tid < NG){                      // need full y0[t]
        while(ALOAD(F0 + tid * FLG_STRIDE) < t + 1) __builtin_amdgcn_s_sleep(1);
      }
      if(t >= RING && tid == 64){        // gx ring backpressure (L1 consumer)
        while(ALOAD(F1 + grp * FLG_STRIDE) < t - RING + 1) __builtin_amdgcn_s_sleep(1);
      }
      __syncthreads();
      int slot = t & (RING - 1);
      for(int i = tid; i < QB * HH; i += SCAN_T){
        int bs = i / HH, k = i - bs * HH;
        vin[bs][k] = ALOAD(&y0r[((size_t)(b0 + bs) * RING + slot) * HH + k]);
      }
      __syncthreads();
      if(act){
        float a0=0.f,a1=0.f,a2=0.f,a3=0.f;
#pragma unroll
        for(int jj = 0; jj < 21; ++jj){
          float4 h0 = *(const float4*)&vin[0][kq*84 + jj*4];
          float4 h1 = *(const float4*)&vin[1][kq*84 + jj*4];
          float4 h2 = *(const float4*)&vin[2][kq*84 + jj*4];
          float4 h3 = *(const float4*)&vin[3][kq*84 + jj*4];
          float w0=wp_[jj*4+0], w1=wp_[jj*4+1], w2=wp_[jj*4+2], w3=wp_[jj*4+3];
          a0 += w0*h0.x + w1*h0.y + w2*h0.z + w3*h0.w;
          a1 += w0*h1.x + w1*h1.y + w2*h1.z + w3*h1.w;
          a2 += w0*h2.x + w1*h2.y + w2*h2.z + w3*h2.w;
          a3 += w0*h3.x + w1*h3.y + w2*h3.z + w3*h3.w;
        }
        part[r][kq][0]=a0; part[r][kq][1]=a1; part[r][kq][2]=a2; part[r][kq][3]=a3;
      }
      __syncthreads();
      if(tid < 504){                     // comb: outI=r, batch=kq
        float s = part[r][0][kq]+part[r][1][kq]+part[r][2][kq]+part[r][3][kq] + bias;
        ASTORE(&gx1r[(((size_t)(b0+kq)*RING + slot)*NG + grp)*126 + r], s);
      }
      __syncthreads();                   // drain before flag
      if(tid == 0) ASTORE(FP + grp * FLG_STRIDE, t + 1);
    }
  } else {
    // ================= L1: GRU layer 1 =================
    float wh[84];
    if(act){
      int gate = r / 42, uu = r - gate * 42;
      const float* wp = Whh1 + (size_t)(gate * HH + u0 + uu) * HH + kq * 84;
#pragma unroll
      for(int j = 0; j < 84; ++j) wh[j] = wp[j];
    }
    float bh_r=0.f, bh_z=0.f, bh_n=0.f;
    if(comb2){
      bh_r = bhh1[u0+cu]; bh_z = bhh1[HH+u0+cu]; bh_n = bhh1[2*HH+u0+cu];
    }
    __syncthreads();
    float hnew = 0.f;
    for(int t = 0; t < TM1; ++t){
      if(t > 0 && tid < NG){
        while(ALOAD(F1 + tid * FLG_STRIDE) < t) __builtin_amdgcn_s_sleep(1);
      }
      if(tid == 64){                     // gx1[t] ready?
        while(ALOAD(FP + grp * FLG_STRIDE) < t + 1) __builtin_amdgcn_s_sleep(1);
      }
      __syncthreads();
      int slot = t & (RING - 1);
      // prefetch gx early: latency hides under h-load + dot
      float gr=0.f, gz=0.f, gn=0.f;
      if(comb2){
        size_t gbase = (((size_t)(b0+cb)*RING + slot)*NG + grp)*126;
        gr = ALOAD(&gx1r[gbase + cu]);
        gz = ALOAD(&gx1r[gbase + 42 + cu]);
        gn = ALOAD(&gx1r[gbase + 84 + cu]);
      }
      float* hcur = h1b + (size_t)(t & 1) * NB * HH;
      float* hnxt = h1b + (size_t)((t + 1) & 1) * NB * HH;
      for(int i = tid; i < QB * HH; i += SCAN_T){
        int bs = i / HH, k = i - bs * HH;
        vin[bs][k] = ALOAD(&hcur[(size_t)(b0 + bs) * HH + k]);
      }
      __syncthreads();
      if(act){
        float a0=0.f,a1=0.f,a2=0.f,a3=0.f;
#pragma unroll
        for(int jj = 0; jj < 21; ++jj){
          float4 h0 = *(const float4*)&vin[0][kq*84 + jj*4];
          float4 h1 = *(const float4*)&vin[1][kq*84 + jj*4];
          float4 h2 = *(const float4*)&vin[2][kq*84 + jj*4];
          float4 h3 = *(const float4*)&vin[3][kq*84 + jj*4];
          float w0=wh[jj*4+0], w1=wh[jj*4+1], w2=wh[jj*4+2], w3=wh[jj*4+3];
          a0 += w0*h0.x + w1*h0.y + w2*h0.z + w3*h0.w;
          a1 += w0*h1.x + w1*h1.y + w2*h1.z + w3*h1.w;
          a2 += w0*h2.x + w1*h2.y + w2*h2.z + w3*h2.w;
          a3 += w0*h3.x + w1*h3.y + w2*h3.z + w3*h3.w;
        }
        part[r][kq][0]=a0; part[r][kq][1]=a1; part[r][kq][2]=a2; part[r][kq][3]=a3;
      }
      __syncthreads();
      if(comb2){
        float ghr = part[cu][0][cb]+part[cu][1][cb]+part[cu][2][cb]+part[cu][3][cb] + bh_r;
        float ghz = part[42+cu][0][cb]+part[42+cu][1][cb]+part[42+cu][2][cb]+part[42+cu][3][cb] + bh_z;
        float ghn = part[84+cu][0][cb]+part[84+cu][1][cb]+part[84+cu][2][cb]+part[84+cu][3][cb] + bh_n;
        float rg = sigm_f(gr + ghr), zg = sigm_f(gz + ghz);
        float ng = tanhf(gn + rg * ghn);
        hnew = (1.f - zg) * ng + zg * vin[cb][u0 + cu];
        ASTORE(&hnxt[(size_t)(b0+cb)*HH + u0+cu], hnew);
      }
      __syncthreads();                   // drain before flag
      if(tid == 0) ASTORE(F1 + grp * FLG_STRIDE, t + 1);
      if(comb2){                         // off critical path
        y1[((size_t)(b0+cb)*TM1 + t)*HH + u0+cu] = hnew;
        if(t == TM1-1) hT1[(size_t)(b0+cb)*HH + u0+cu] = hnew;
      }
    }
  }
}

// ---------------- fused conv stack + dense head (32-t tile, static LDS 45.6KB) ----------------
__global__ __launch_bounds__(256) void k_head(const float* __restrict__ y1,
   const float* __restrict__ W2, const float* __restrict__ b2,
   const float* __restrict__ W3, const float* __restrict__ b3,
   const float* __restrict__ W3z, const float* __restrict__ b3z,
   const float* __restrict__ Wza, const float* __restrict__ bza,
   const float* __restrict__ W4, const float* __restrict__ b4,
   const float* __restrict__ W5, const float* __restrict__ b5,
   const float* __restrict__ gmm, const float* __restrict__ bet,
   const float* __restrict__ Wc, const float* __restrict__ bc,
   float* __restrict__ out_affs, float* __restrict__ out_lab){
  __shared__ float sm[11402];
  float* aggp = sm;             // [5*32][38]  6080
  float* zinp = sm + 6080;      // [64][36]    2304
  float* zzp  = sm + 8384;      // [64][34]    2176 -> ends 10560
  float* ystp = sm + 10560;     // [42][17]    714  -> ends 11274
  float* affp = sm + 11274;     // [4][32]     128  -> ends 11402
  float* lblA = sm + 6080;      // [128][32]   4096 (aliases zin+zz, dead by then)
  float* lgpp = sm;             // [32][8][4]  1024 (aliases aggp, dead by then)
  int t0 = blockIdx.x * 32;
  int b  = blockIdx.y;
  int tid = threadIdx.x;

  for(int i = tid; i < 6080; i += 256) aggp[i] = 0.f;
  for(int i = tid; i < 2304; i += 256) zinp[i] = 0.f;
  __syncthreads();

  const int   vg_[21] = {0,3,3,3,3,4,4,4,4,0,0,0,0,1,1,1,1,2,2,2,2};
  const float vw_[21] = {0.1f,0.1f,0.2f,0.3f,0.4f,0.1f,0.2f,0.3f,0.4f,
                         0.1f,0.2f,0.2f,0.4f,0.1f,0.2f,0.3f,0.4f,0.1f,0.2f,0.3f,0.4f};

  {
    int o = tid >> 3, q = tid & 7;
    for(int v = 0; v < NV; ++v){
      for(int idx = tid; idx < 42 * 16; idx += 256){
        int ts = idx >> 4, i = idx & 15; int t = t0 - 5 + ts;
        ystp[ts * 17 + i] = (t >= 0 && t < TM1) ? y1[((size_t)b * TM1 + t) * HH + v * 16 + i] : 0.f;
      }
      __syncthreads();
      int g = vg_[v]; float wv = vw_[v];
      const float* wp = W2 + v * 2560 + o * 80;
      float acc5[5];
      float bias = b2[v * 32 + o];
#pragma unroll
      for(int j = 0; j < 5; ++j) acc5[j] = bias;
#pragma unroll
      for(int i = 0; i < 16; ++i){
        float w0 = wp[i*5+0], w1 = wp[i*5+1], w2v = wp[i*5+2], w3v = wp[i*5+3], w4v = wp[i*5+4];
#pragma unroll
        for(int j = 0; j < 5; ++j){
          int ts = q * 5 + j;
          if(ts < 38){
            acc5[j] += w0*ystp[ts*17+i] + w1*ystp[(ts+1)*17+i] + w2v*ystp[(ts+2)*17+i]
                     + w3v*ystp[(ts+3)*17+i] + w4v*ystp[(ts+4)*17+i];
          }
        }
      }
#pragma unroll
      for(int j = 0; j < 5; ++j){
        int ts = q * 5 + j;
        if(ts < 38){
          int t = t0 - 3 + ts;
          if(t >= 0 && t < TM1) aggp[(g * 32 + o) * 38 + ts] += wv * elu_f(acc5[j]);
        }
      }
      __syncthreads();
    }
  }

  {
    int c = tid >> 2, q = tid & 3;
    for(int k5 = 0; k5 < 5; ++k5){
      float coef = (k5 == 0) ? 0.12f : 0.22f;
      const float* wp = W3 + k5 * 6144 + c * 96;
      float accv[9];
      float bias = b3[k5 * 64 + c];
#pragma unroll
      for(int j = 0; j < 9; ++j) accv[j] = bias;
      for(int i = 0; i < 32; ++i){
        float w0 = wp[i*3+0], w1 = wp[i*3+1], w2v = wp[i*3+2];
        const float* ap = &aggp[(k5 * 32 + i) * 38 + q * 9];
#pragma unroll
        for(int j = 0; j < 9; ++j)
          accv[j] += w0*ap[j] + w1*ap[j+1] + w2v*ap[j+2];
      }
      __syncthreads();
#pragma unroll
      for(int j = 0; j < 9; ++j){
        int ts = q * 9 + j;
        int t = t0 - 2 + ts;
        if(t >= 0 && t < TM1) zinp[c * 36 + ts] += coef * elu_f(accv[j]);
      }
      __syncthreads();
    }
  }

  {
    int c = tid >> 2, q = tid & 3;
    const float* wp = W3z + c * 192;
    float accv[9];
    float bias = b3z[c];
#pragma unroll
    for(int j = 0; j < 9; ++j) accv[j] = bias;
    for(int i = 0; i < 64; ++i){
      float w0 = wp[i*3+0], w1 = wp[i*3+1], w2v = wp[i*3+2];
      const float* zp = &zinp[i * 36 + q * 9];
#pragma unroll
      for(int j = 0; j < 9; ++j)
        accv[j] += w0*zp[j] + w1*zp[j+1] + w2v*zp[j+2];
    }
    __syncthreads();
#pragma unroll
    for(int j = 0; j < 9; ++j){
      int ts = q * 9 + j;
      if(ts < 34){
        int t = t0 - 1 + ts;
        zzp[c * 34 + ts] = (t >= 0 && t < TM1) ? elu_f(accv[j]) : 0.f;
      }
    }
    __syncthreads();
  }

  if(tid < 128){
    int a = tid >> 5, tt = tid & 31;
    const float* wp = Wza + a * 192;
    float acc = bza[a];
    for(int i = 0; i < 64; ++i){
      const float* zp = &zzp[i * 34 + tt];
      acc += wp[i*3+0]*zp[0] + wp[i*3+1]*zp[1] + wp[i*3+2]*zp[2];
    }
    float av = elu_f(acc);
    affp[a * 32 + tt] = av;
    int t = t0 + tt;
    if(t < TM1) out_affs[((size_t)b * TM1 + t) * 4 + a] = av;
  }
  __syncthreads();

  for(int idx = tid; idx < 4096; idx += 256){
    int d = idx >> 5, tt = idx & 31;
    float acc = b4[d] + W4[d*4+0]*affp[tt] + W4[d*4+1]*affp[32+tt]
              + W4[d*4+2]*affp[64+tt] + W4[d*4+3]*affp[96+tt];
    lblA[idx] = elu_f(acc);
  }
  __syncthreads();

  {
    int tt = tid >> 3, dg = tid & 7;
    float l2[16];
#pragma unroll
    for(int dd = 0; dd < 16; ++dd) l2[dd] = b5[dg * 16 + dd];
    for(int cc = 0; cc < 128; ++cc){
      float xv = lblA[cc * 32 + tt];
#pragma unroll
      for(int dd = 0; dd < 16; ++dd)
        l2[dd] += W5[(dg * 16 + dd) * 128 + cc] * xv;
    }
    int t = t0 + tt;
    float sc = 0.f, bb = 0.f;
    if(t < TM1){ sc = gmm[t] * rsqrtf(1.f + 1e-5f); bb = bet[t]; }
    float lg[4] = {0.f, 0.f, 0.f, 0.f};
#pragma unroll
    for(int dd = 0; dd < 16; ++dd){
      int d = dg * 16 + dd;
      float val = elu_f(l2[dd]) * sc + bb;
#pragma unroll
      for(int c = 0; c < 4; ++c) lg[c] += Wc[c * 128 + d] * val;
    }
    __syncthreads();
#pragma unroll
    for(int c = 0; c < 4; ++c) lgpp[(tt * 8 + dg) * 4 + c] = lg[c];
  }
  __syncthreads();
  if(tid < 128){
    int tt = tid >> 2, c = tid & 3;
    float s = bc[c];
#pragma unroll
    for(int dg = 0; dg < 8; ++dg) s += lgpp[(tt * 8 + dg) * 4 + c];
    int ta = t0 + tt;
    if(ta < TM1) out_lab[((size_t)b * TM1 + ta) * 4 + c] = sigm_f(s);
  }
}

extern "C" void kernel_launch(void* const* d_in, const int* in_sizes, int n_in,
                              void* d_out, int out_size, void* d_ws, size_t ws_size,
                              hipStream_t stream){
  (void)in_sizes; (void)n_in; (void)out_size; (void)ws_size;
  const float* x_diffs = (const float*)d_in[1];
  const float* h_init  = (const float*)d_in[3];
  const float* Wih0 = (const float*)d_in[4];
  const float* Whh0 = (const float*)d_in[5];
  const float* bih0 = (const float*)d_in[6];
  const float* bhh0 = (const float*)d_in[7];
  const float* Wih1 = (const float*)d_in[8];
  const float* Whh1 = (const float*)d_in[9];
  const float* bih1 = (const float*)d_in[10];
  const float* bhh1 = (const float*)d_in[11];
  const float* W2  = (const float*)d_in[12];
  const float* b2  = (const float*)d_in[13];
  const float* W3  = (const float*)d_in[14];
  const float* b3  = (const float*)d_in[15];
  const float* W3z = (const float*)d_in[16];
  const float* b3z = (const float*)d_in[17];
  const float* Wza = (const float*)d_in[18];
  const float* bza = (const float*)d_in[19];
  const float* W4  = (const float*)d_in[20];
  const float* b4  = (const float*)d_in[21];
  const float* W5  = (const float*)d_in[22];
  const float* b5  = (const float*)d_in[23];
  const float* gmm = (const float*)d_in[24];
  const float* bet = (const float*)d_in[25];
  const float* Wc  = (const float*)d_in[26];
  const float* bc  = (const float*)d_in[27];
  float* out = (float*)d_out;

  // workspace layout (floats): ~127 MB total
  float* ws   = (float*)d_ws;
  float* x_ws = ws;                         // 32*2047*63   = 4,126,752 ([b][t][63])
  float* y1   = x_ws + 4126752;             // 32*2047*336  = 22,009,344
  float* y0r  = y1 + 22009344;              // 32*128*336   =  1,376,256
  float* gx1r = y0r + 1376256;              // 32*128*1008  =  4,128,768
  float* hb   = gx1r + 4128768;             // 4*32*336     =     43,008
  int*   flg  = (int*)(hb + 43008);         // 3 * 64 * FLG_STRIDE ints

  float* h0b = hb;
  float* h1b = hb + 2 * NB * HH;
  int* flg0 = flg;
  int* flgP = flg + 64 * FLG_STRIDE;
  int* flg1 = flg + 128 * FLG_STRIDE;

  float* out_affs = out;
  float* out_lab  = out + (size_t)NB * TM1 * 4;
  float* hT0 = out + 2 * (size_t)NB * TM1 * 4;
  float* hT1 = hT0 + NB * HH;

  (void)hipMemsetAsync(flg, 0, 3 * 64 * FLG_STRIDE * sizeof(int), stream);
  (void)hipMemcpyAsync(h0b, h_init,           NB * HH * sizeof(float), hipMemcpyDeviceToDevice, stream);
  (void)hipMemcpyAsync(h1b, h_init + NB * HH, NB * HH * sizeof(float), hipMemcpyDeviceToDevice, stream);

  k_euler<<<dim3(NB * NV), 256, 0, stream>>>(x_diffs, x_ws);

  k_fused<<<dim3(192), SCAN_T, 0, stream>>>(
      Whh0, bhh0, Wih0, bih0, Whh1, bhh1, Wih1, bih1, x_ws,
      h0b, h1b, y0r, gx1r, y1, hT0, hT1, flg0, flgP, flg1);

  k_head<<<dim3(64, NB), 256, 0, stream>>>(y1, W2, b2, W3, b3, W3z, b3z, Wza, bza,
                                           W4, b4, W5, b5, gmm, bet, Wc, bc,
                                           out_affs, out_lab);
}